// Round 12
// baseline (1845.398 us; speedup 1.0000x reference)
//
#include <hip/hip_runtime.h>
#include <hip/hip_bf16.h>

// Problem constants
constexpr int Bn  = 8;
constexpr int Cn  = 192;   // hidden channels
constexpr int Tn  = 1024;  // sequence length
constexpr int Hn  = 2;     // heads
constexpr int DKn = 96;    // head dim
constexpr int FCn = 768;   // filter channels
constexpr int Ln  = 6;     // layers
constexpr int WINn = 4;    // rel-attn window
constexpr int QKS = 384;   // QK transposed row stride (Q|K concat)
constexpr int NSPLIT = 4;  // attention s-split (flash-decoding)
constexpr int RN  = Bn * Hn * Tn;  // 16384 attention rows

typedef __hip_bfloat16 bf16;
typedef __attribute__((ext_vector_type(8))) short short8;
typedef __attribute__((ext_vector_type(4))) float f32x4;

// ---------------------------------------------------------------------------
// One-time transforms
__global__ void cast_bf(const float* __restrict__ src, bf16* __restrict__ dst, int n) {
    int i = blockIdx.x * 256 + threadIdx.x;
    if (i < n) dst[i] = __float2bfloat16(src[i]);
}

// w [L][CO][CIN][3] -> [L][3][CO][CIN] bf16
__global__ void reorder_w(const float* __restrict__ src, bf16* __restrict__ dst,
                          int CO, int CIN) {
    int i = blockIdx.x * 256 + threadIdx.x;
    int n = Ln * 3 * CO * CIN;
    if (i >= n) return;
    int c = i % CIN;
    int f = (i / CIN) % CO;
    int ko = (i / (CIN * CO)) % 3;
    int l = i / (3 * CIN * CO);
    dst[i] = __float2bfloat16(src[(((size_t)(l * CO + f)) * CIN + c) * 3 + ko]);
}

// erk fp32 [L][9][96] -> bf16 [L][16][96], rows 9..15 zero (MFMA B-frag ready)
__global__ void erk_prep(const float* __restrict__ src, bf16* __restrict__ dst) {
    int i = blockIdx.x * 256 + threadIdx.x;       // < Ln*16*96
    if (i >= Ln * 16 * 96) return;
    int d = i % 96, row = (i / 96) % 16, l = i / (96 * 16);
    float v = (row < 9) ? src[((size_t)l * 9 + row) * 96 + d] : 0.f;
    dst[i] = __float2bfloat16(v);
}

// Build fused QKV weight [L][576][C] bf16 (qscale folded into Q) + bias fp32
__global__ void qkv_prep(const float* __restrict__ Wq, const float* __restrict__ Wk,
                         const float* __restrict__ Wv, const float* __restrict__ bq,
                         const float* __restrict__ bk, const float* __restrict__ bv,
                         bf16* __restrict__ Wout, float* __restrict__ bout, float qscale) {
    int i = blockIdx.x * 256 + threadIdx.x;
    const int nW = Ln * 576 * Cn;
    if (i < nW) {
        int c = i % Cn, f = (i / Cn) % 576, l = i / (Cn * 576);
        float v;
        if (f < 192)      v = Wq[((size_t)l * Cn + f) * Cn + c] * qscale;
        else if (f < 384) v = Wk[((size_t)l * Cn + f - 192) * Cn + c];
        else              v = Wv[((size_t)l * Cn + f - 384) * Cn + c];
        Wout[i] = __float2bfloat16(v);
    } else if (i < nW + Ln * 576) {
        int j = i - nW, f = j % 576, l = j / 576;
        float v;
        if (f < 192)      v = bq[l * Cn + f] * qscale;
        else if (f < 384) v = bk[l * Cn + f - 192];
        else              v = bv[l * Cn + f - 384];
        bout[j] = v;
    }
}

// ---------------------------------------------------------------------------
// Input: X = x*mask (fp32, NCT) + XT = bf16 transposed [b][t][c]
__global__ __launch_bounds__(256) void cvt_in_k(
        const float* __restrict__ x, const float* __restrict__ mask,
        float* __restrict__ X, bf16* __restrict__ XT) {
    __shared__ float tile[Cn][33];
    const int tid = threadIdx.x, lane = tid & 31, w = tid >> 5;
    const int b = blockIdx.x >> 5;
    const int t0 = (blockIdx.x & 31) * 32;
    const float mk = mask[b * Tn + t0 + lane];
    for (int c = w; c < Cn; c += 8) {
        float v = x[((b * Cn + c) * Tn) + t0 + lane] * mk;
        X[((b * Cn + c) * Tn) + t0 + lane] = v;
        tile[c][lane] = v;
    }
    __syncthreads();
    for (int idx = tid; idx < 32 * Cn; idx += 256) {
        int tl = idx / Cn, c = idx % Cn;
        XT[((size_t)b * Tn + t0 + tl) * Cn + c] = __float2bfloat16(tile[c][tl]);
    }
}

// ---------------------------------------------------------------------------
// MFMA conv1d, software-pipelined (double-buffered fragments), optional K-split.
// MODE 0: fp32 NCT out (+bias, *mask if mask!=null)
// MODE 2: bf16 transposed [b][t][CO] out relu(+bias)*mask   [FFN1]
// MODE 4: QKV split: f<384 -> bf16 T (stride QKS) into Y0; else bf16 NCT Y1
// MODE 5: fp32 NCT K-split partial, NO bias: ks==0 -> Y0, ks==1 -> Y1 [FFN2]
template <int KS, int TT, int MODE, int NSP>
__global__ __launch_bounds__(256) void conv_mfma(
        const bf16* __restrict__ Xt, const bf16* __restrict__ W,
        const float* __restrict__ bias, const float* __restrict__ mask,
        void* __restrict__ Y0, void* __restrict__ Y1, int CIN, int CO) {
    constexpr int PAD = KS / 2;
    constexpr int NMB = TT / 16;
    const int tid = threadIdx.x;
    const int wv = tid >> 6, lane = tid & 63;
    const int m = lane & 15, kq = lane >> 4;
    const int b = blockIdx.z / NSP, ks = blockIdx.z % NSP;
    const int t0 = blockIdx.x * TT;
    const int f = blockIdx.y * 64 + wv * 16 + m;

    const bf16* xbase = Xt + (size_t)b * Tn * CIN + kq * 8;
    const bf16* wrow = W + (size_t)f * CIN + kq * 8;
    const size_t wko = (size_t)CO * CIN;

    f32x4 acc[NMB] = {};
    short8 A0[NMB][KS], B0[KS], A1[NMB][KS], B1[KS];

    auto LOAD = [&](int c0, short8 (&A)[NMB][KS], short8 (&Bf)[KS]) {
#pragma unroll
        for (int ko = 0; ko < KS; ++ko) {
            Bf[ko] = *(const short8*)(wrow + ko * wko + c0);
#pragma unroll
            for (int mb = 0; mb < NMB; ++mb) {
                int tr = t0 + mb * 16 + m + ko - PAD;
                short8 a = {0, 0, 0, 0, 0, 0, 0, 0};
                if (PAD == 0 || (unsigned)tr < (unsigned)Tn)
                    a = *(const short8*)(xbase + (size_t)tr * CIN + c0);
                A[mb][ko] = a;
            }
        }
    };
    auto STEP = [&](short8 (&A)[NMB][KS], short8 (&Bf)[KS]) {
#pragma unroll
        for (int ko = 0; ko < KS; ++ko)
#pragma unroll
            for (int mb = 0; mb < NMB; ++mb)
                acc[mb] = __builtin_amdgcn_mfma_f32_16x16x32_bf16(A[mb][ko], Bf[ko], acc[mb], 0, 0, 0);
    };

    const int cbeg = ks * (CIN / NSP);
    const int cend = cbeg + CIN / NSP;
    LOAD(cbeg, A0, B0);
    for (int c0 = cbeg; c0 < cend; c0 += 64) {   // (CIN/NSP) % 64 == 0
        if (c0 + 32 < cend) LOAD(c0 + 32, A1, B1);
        STEP(A0, B0);
        if (c0 + 64 < cend) LOAD(c0 + 64, A0, B0);
        STEP(A1, B1);
    }

    if (MODE == 5) {
        float* Y = (float*)(ks ? Y1 : Y0) + ((size_t)b * CO + f) * Tn;
#pragma unroll
        for (int mb = 0; mb < NMB; ++mb) {
            int t = t0 + mb * 16 + kq * 4;
            float4 o;
            o.x = acc[mb][0]; o.y = acc[mb][1]; o.z = acc[mb][2]; o.w = acc[mb][3];
            *(float4*)(Y + t) = o;
        }
        return;
    }
    const float bs = bias[f];
    if (MODE == 0) {
        float* Y = (float*)Y0 + ((size_t)b * CO + f) * Tn;
#pragma unroll
        for (int mb = 0; mb < NMB; ++mb) {
            int t = t0 + mb * 16 + kq * 4;
            float4 o;
            o.x = acc[mb][0] + bs; o.y = acc[mb][1] + bs;
            o.z = acc[mb][2] + bs; o.w = acc[mb][3] + bs;
            if (mask) {
                o.x *= mask[b * Tn + t];     o.y *= mask[b * Tn + t + 1];
                o.z *= mask[b * Tn + t + 2]; o.w *= mask[b * Tn + t + 3];
            }
            *(float4*)(Y + t) = o;
        }
    } else if (MODE == 2) {
        bf16* Y = (bf16*)Y0;
#pragma unroll
        for (int mb = 0; mb < NMB; ++mb)
#pragma unroll
            for (int r = 0; r < 4; ++r) {
                int t = t0 + mb * 16 + kq * 4 + r;
                float v = fmaxf(acc[mb][r] + bs, 0.f) * mask[b * Tn + t];
                Y[((size_t)b * Tn + t) * CO + f] = __float2bfloat16(v);
            }
    } else {  // MODE 4
        if (blockIdx.y < 6) {          // Q|K -> transposed, stride QKS
            bf16* Y = (bf16*)Y0;
#pragma unroll
            for (int mb = 0; mb < NMB; ++mb)
#pragma unroll
                for (int r = 0; r < 4; ++r) {
                    int t = t0 + mb * 16 + kq * 4 + r;
                    Y[((size_t)b * Tn + t) * QKS + f] = __float2bfloat16(acc[mb][r] + bs);
                }
        } else {                        // V -> bf16 NCT
            bf16* Y = (bf16*)Y1 + ((size_t)b * Cn + f - 384) * Tn;
#pragma unroll
            for (int mb = 0; mb < NMB; ++mb) {
                int t = t0 + mb * 16 + kq * 4;
                bf16 tmp[4];
#pragma unroll
                for (int r = 0; r < 4; ++r) tmp[r] = __float2bfloat16(acc[mb][r] + bs);
                *(uint2*)(Y + t) = *(uint2*)tmp;
            }
        }
    }
}

// ---------------------------------------------------------------------------
// MFMA flash attention, split-K over s, software-pipelined chunk loop.
// QK: bf16 [b][t][384] (Q pre-scaled cols 0..191, K cols 192..383), V: bf16
// NCT, erkb: bf16 [L][16][96]. 256 thr = 4 waves, 16 q-rows/wave.
// K B-frags double-buffered (chunk i+1 prefetched during chunk i softmax/PV);
// V B-frags issued at loop top (latency hides under S-MFMA+softmax).
// Grid (T/64, H, B*NSPLIT). Barrier-free: all LDS per-wave.
// Writes UNNORMALIZED partials: Op bf16 [sp][rid][96], Mp/Lp fp32 [sp][rid].
__global__ __launch_bounds__(256) void attn_mfma(
        const bf16* __restrict__ QK, const bf16* __restrict__ V,
        const float* __restrict__ mask, const bf16* __restrict__ erkb,
        const float* __restrict__ erv, bf16* __restrict__ Op,
        float* __restrict__ Mp, float* __restrict__ Lp, int layer) {
    __shared__ float rq[4][16][17];   // per-wave rel-K band: [m][dd]
    __shared__ bf16 pT[4][16][72];    // per-wave P: [m][s]

    const int tid = threadIdx.x, wv = tid >> 6, lane = tid & 63;
    const int col = lane & 15, quad = lane >> 4;
    const int t0 = blockIdx.x * 64, h = blockIdx.y;
    const int b = blockIdx.z / NSPLIT, sp = blockIdx.z % NSPLIT;
    const int hd = h * DKn;
    const int t0w = t0 + wv * 16;
    constexpr int CH = Tn / NSPLIT / 64;   // chunks per block = 4

    // Q A-frags (persist): A[m=col][k=quad*8+j+32*kd]
    short8 aq[3];
    {
        const bf16* qrow = QK + ((size_t)b * Tn + t0w + col) * QKS + hd + quad * 8;
#pragma unroll
        for (int kd = 0; kd < 3; ++kd) aq[kd] = *(const short8*)(qrow + kd * 32);
    }
    // rel-K band via MFMA: R = Q . erk^T  (B rows 9..15 are zero)
    {
        const bf16* erow = erkb + ((size_t)layer * 16 + col) * 96 + quad * 8;
        f32x4 R = {};
#pragma unroll
        for (int kd = 0; kd < 3; ++kd) {
            short8 be = *(const short8*)(erow + kd * 32);
            R = __builtin_amdgcn_mfma_f32_16x16x32_bf16(aq[kd], be, R, 0, 0, 0);
        }
#pragma unroll
        for (int r = 0; r < 4; ++r) rq[wv][quad * 4 + r][col] = R[r];
    }
    float mtv[4];
#pragma unroll
    for (int r = 0; r < 4; ++r) mtv[r] = mask[b * Tn + t0w + quad * 4 + r];

    float mold[4] = {-3.0e38f, -3.0e38f, -3.0e38f, -3.0e38f};
    float lrow[4] = {};
    f32x4 O[6] = {};
    const float* ervl = erv + (size_t)layer * 9 * DKn;

    const int sbeg = sp * (Tn / NSPLIT);

    // K-fragment double buffer
    short8 bk[2][4][3];
    auto LOADK = [&](int s0, short8 (&dst)[4][3]) {
#pragma unroll
        for (int nb = 0; nb < 4; ++nb) {
            const bf16* krow = QK + ((size_t)b * Tn + s0 + 16 * nb + col) * QKS + 192 + hd + quad * 8;
#pragma unroll
            for (int kd = 0; kd < 3; ++kd) dst[nb][kd] = *(const short8*)(krow + kd * 32);
        }
    };
    LOADK(sbeg, bk[0]);

#pragma unroll
    for (int it = 0; it < CH; ++it) {
        const int s0 = sbeg + it * 64;
        // V B-frags for this chunk (issued early; consumed after softmax)
        short8 bv[6][2];
#pragma unroll
        for (int nd = 0; nd < 6; ++nd) {
            const bf16* vrow = V + ((size_t)(b * Cn + hd + 16 * nd + col)) * Tn + s0 + quad * 8;
#pragma unroll
            for (int kk = 0; kk < 2; ++kk) bv[nd][kk] = *(const short8*)(vrow + kk * 32);
        }

        // S = Q K^T  (current bk buffer)
        f32x4 S[4] = {};
#pragma unroll
        for (int nb = 0; nb < 4; ++nb)
#pragma unroll
            for (int kd = 0; kd < 3; ++kd)
                S[nb] = __builtin_amdgcn_mfma_f32_16x16x32_bf16(
                    aq[kd], bk[it & 1][nb][kd], S[nb], 0, 0, 0);

        // prefetch next chunk's K (hides under softmax + PV below)
        if (it + 1 < CH) LOADK(s0 + 64, bk[(it + 1) & 1]);

        // rel-K band + mask  (C layout: row=quad*4+r, col = lane&15)
#pragma unroll
        for (int nb = 0; nb < 4; ++nb) {
            const int sg = s0 + 16 * nb + col;
            const float msv = mask[b * Tn + sg];
#pragma unroll
            for (int r = 0; r < 4; ++r) {
                const int tq = t0w + quad * 4 + r;
                float v = S[nb][r];
                int dd = sg - tq + WINn;
                if (dd >= 0 && dd <= 2 * WINn) v += rq[wv][quad * 4 + r][dd];
                if (msv * mtv[r] == 0.f) v = -1e4f;
                S[nb][r] = v;
            }
        }

        // online softmax (16-lane shuffle reductions)
        float mnew[4], alpha[4], psum[4];
#pragma unroll
        for (int r = 0; r < 4; ++r) {
            float mc = fmaxf(fmaxf(S[0][r], S[1][r]), fmaxf(S[2][r], S[3][r]));
#pragma unroll
            for (int mk2 = 1; mk2 < 16; mk2 <<= 1) mc = fmaxf(mc, __shfl_xor(mc, mk2));
            mnew[r] = fmaxf(mold[r], mc);
            alpha[r] = (mold[r] <= -1.0e30f) ? 0.f : __expf(mold[r] - mnew[r]);
            mold[r] = mnew[r];
            psum[r] = 0.f;
        }
#pragma unroll
        for (int nb = 0; nb < 4; ++nb)
#pragma unroll
            for (int r = 0; r < 4; ++r) {
                bf16 pb = __float2bfloat16(__expf(S[nb][r] - mnew[r]));
                pT[wv][quad * 4 + r][16 * nb + col] = pb;
                psum[r] += __bfloat162float(pb);
            }
#pragma unroll
        for (int r = 0; r < 4; ++r) {
#pragma unroll
            for (int mk2 = 1; mk2 < 16; mk2 <<= 1) psum[r] += __shfl_xor(psum[r], mk2);
            lrow[r] = lrow[r] * alpha[r] + psum[r];
#pragma unroll
            for (int nd = 0; nd < 6; ++nd) O[nd][r] *= alpha[r];
        }

        // P A-frags from per-wave LDS; PV
        short8 aP[2];
#pragma unroll
        for (int kk = 0; kk < 2; ++kk)
            aP[kk] = *(const short8*)&pT[wv][col][kk * 32 + quad * 8];
#pragma unroll
        for (int nd = 0; nd < 6; ++nd)
#pragma unroll
            for (int kk = 0; kk < 2; ++kk)
                O[nd] = __builtin_amdgcn_mfma_f32_16x16x32_bf16(aP[kk], bv[nd][kk], O[nd], 0, 0, 0);

        // rel-V on diagonal chunks
        if (s0 <= t0w + 15 + WINn && s0 + 63 >= t0w - WINn) {
#pragma unroll
            for (int r = 0; r < 4; ++r) {
                const int tq = t0w + quad * 4 + r;
                for (int dd = 0; dd <= 2 * WINn; ++dd) {
                    int sg = tq + dd - WINn;
                    if (sg >= s0 && sg < s0 + 64) {
                        float p = __bfloat162float(pT[wv][quad * 4 + r][sg - s0]);
#pragma unroll
                        for (int nd = 0; nd < 6; ++nd)
                            O[nd][r] += p * ervl[dd * DKn + 16 * nd + col];
                    }
                }
            }
        }
    }

    // epilogue: write unnormalized partials
    const int rbase = (b * Hn + h) * Tn + t0w;
#pragma unroll
    for (int r = 0; r < 4; ++r) {
        const int rid = rbase + quad * 4 + r;
        bf16* dst = Op + ((size_t)sp * RN + rid) * 96 + col;
#pragma unroll
        for (int nd = 0; nd < 6; ++nd)
            dst[16 * nd] = __float2bfloat16(O[nd][r]);
        if (col == 0) {
            Mp[sp * RN + rid] = mold[r];
            Lp[sp * RN + rid] = lrow[r];
        }
    }
}

// Combine split partials -> AT bf16 [b][t][C]. One thread per (rid, 8-chan).
__global__ __launch_bounds__(256) void attn_combine(
        const bf16* __restrict__ Op, const float* __restrict__ Mp,
        const float* __restrict__ Lp, bf16* __restrict__ AT) {
    int i = blockIdx.x * 256 + threadIdx.x;       // < RN*12
    int rid = i / 12, j = i - rid * 12;
    float m[NSPLIT], l[NSPLIT], mx = -3.0e38f;
#pragma unroll
    for (int s = 0; s < NSPLIT; ++s) {
        m[s] = Mp[s * RN + rid];
        l[s] = Lp[s * RN + rid];
        mx = fmaxf(mx, m[s]);
    }
    float denom = 0.f;
    float o[8] = {};
#pragma unroll
    for (int s = 0; s < NSPLIT; ++s) {
        float sc = __expf(m[s] - mx);
        denom += sc * l[s];
        short8 v = *(const short8*)(Op + ((size_t)s * RN + rid) * 96 + j * 8);
        const bf16* vb = (const bf16*)&v;
#pragma unroll
        for (int e = 0; e < 8; ++e) o[e] += sc * __bfloat162float(vb[e]);
    }
    float inv = 1.f / denom;
    int t = rid & (Tn - 1), h = (rid >> 10) & (Hn - 1), b = rid >> 11;
    bf16 outv[8];
#pragma unroll
    for (int e = 0; e < 8; ++e) outv[e] = __float2bfloat16(o[e] * inv);
    *(uint4*)(AT + ((size_t)b * Tn + t) * Cn + h * DKn + j * 8) = *(uint4*)outv;
}

// ---------------------------------------------------------------------------
// Residual add + LayerNorm over channels. X <- LN(X+Y)*g+b (fp32) and
// XT <- bf16 transposed [b][t][C], optionally *mask.
__global__ __launch_bounds__(256) void ln_k(
        float* __restrict__ X, const float* __restrict__ Y,
        const float* __restrict__ G, const float* __restrict__ Bt,
        const float* __restrict__ mask, bf16* __restrict__ XT, int apply_mask) {
    __shared__ float tile[Cn][33];
    __shared__ float r1[8][32];
    __shared__ float r2[8][32];
    const int tid = threadIdx.x;
    const int lane = tid & 31, w = tid >> 5;
    const int b = blockIdx.x >> 5;
    const int t0 = (blockIdx.x & 31) * 32;
    const int t = t0 + lane;

    float s1 = 0.f, s2 = 0.f;
    for (int c = w; c < Cn; c += 8) {
        float v = X[((b * Cn + c) * Tn) + t] + Y[((b * Cn + c) * Tn) + t];
        tile[c][lane] = v;
        s1 += v;
        s2 += v * v;
    }
    r1[w][lane] = s1;
    r2[w][lane] = s2;
    __syncthreads();
    if (w == 0) {
        float a = 0.f, q = 0.f;
        for (int i = 0; i < 8; ++i) { a += r1[i][lane]; q += r2[i][lane]; }
        float m = a / Cn;
        float var = q / Cn - m * m;
        r1[0][lane] = m;
        r2[0][lane] = rsqrtf(var + 1e-5f);
    }
    __syncthreads();
    const float m = r1[0][lane], rs = r2[0][lane];
    for (int c = w; c < Cn; c += 8) {
        float y = (tile[c][lane] - m) * rs * G[c] + Bt[c];
        X[((b * Cn + c) * Tn) + t] = y;
        tile[c][lane] = y;
    }
    __syncthreads();
    for (int idx = tid; idx < 32 * Cn; idx += 256) {
        int tl = idx / Cn, c = idx % Cn;
        float v = tile[c][tl];
        if (apply_mask) v *= mask[b * Tn + t0 + tl];
        XT[((size_t)b * Tn + t0 + tl) * Cn + c] = __float2bfloat16(v);
    }
}

// FFN2-combine + residual + LN2: Y = (P0+P1+bias)*mask; Xn = LN(X+Y)*g+b.
// OUT==null: X <- Xn, XT <- bf16(Xn).  OUT!=null (last layer): OUT <- Xn*mask.
__global__ __launch_bounds__(256) void ln_ffn2(
        float* __restrict__ X, const float* __restrict__ P0,
        const float* __restrict__ P1, const float* __restrict__ bias,
        const float* __restrict__ G, const float* __restrict__ Bt,
        const float* __restrict__ mask, bf16* __restrict__ XT,
        float* __restrict__ OUT) {
    __shared__ float tile[Cn][33];
    __shared__ float r1[8][32];
    __shared__ float r2[8][32];
    const int tid = threadIdx.x;
    const int lane = tid & 31, w = tid >> 5;
    const int b = blockIdx.x >> 5;
    const int t0 = (blockIdx.x & 31) * 32;
    const int t = t0 + lane;
    const float mk = mask[b * Tn + t];

    float s1 = 0.f, s2 = 0.f;
    for (int c = w; c < Cn; c += 8) {
        size_t i = ((size_t)b * Cn + c) * Tn + t;
        float y = (P0[i] + P1[i] + bias[c]) * mk;
        float v = X[i] + y;
        tile[c][lane] = v;
        s1 += v;
        s2 += v * v;
    }
    r1[w][lane] = s1;
    r2[w][lane] = s2;
    __syncthreads();
    if (w == 0) {
        float a = 0.f, q = 0.f;
        for (int i = 0; i < 8; ++i) { a += r1[i][lane]; q += r2[i][lane]; }
        float m = a / Cn;
        float var = q / Cn - m * m;
        r1[0][lane] = m;
        r2[0][lane] = rsqrtf(var + 1e-5f);
    }
    __syncthreads();
    const float m = r1[0][lane], rs = r2[0][lane];
    if (OUT) {   // final layer: write output = LN(...)*mask directly, done
        for (int c = w; c < Cn; c += 8) {
            float y = (tile[c][lane] - m) * rs * G[c] + Bt[c];
            OUT[((b * Cn + c) * Tn) + t] = y * mk;
        }
        return;
    }
    for (int c = w; c < Cn; c += 8) {
        float y = (tile[c][lane] - m) * rs * G[c] + Bt[c];
        X[((b * Cn + c) * Tn) + t] = y;
        tile[c][lane] = y;
    }
    __syncthreads();
    for (int idx = tid; idx < 32 * Cn; idx += 256) {
        int tl = idx / Cn, c = idx % Cn;
        XT[((size_t)b * Tn + t0 + tl) * Cn + c] = __float2bfloat16(tile[c][tl]);
    }
}

// ---------------------------------------------------------------------------
extern "C" void kernel_launch(void* const* d_in, const int* in_sizes, int n_in,
                              void* d_out, int out_size, void* d_ws, size_t ws_size,
                              hipStream_t stream) {
    const float* x    = (const float*)d_in[0];
    const float* mask = (const float*)d_in[1];
    const float* Wq   = (const float*)d_in[2];
    const float* bq   = (const float*)d_in[3];
    const float* Wk   = (const float*)d_in[4];
    const float* bk   = (const float*)d_in[5];
    const float* Wv   = (const float*)d_in[6];
    const float* bv   = (const float*)d_in[7];
    const float* Wo   = (const float*)d_in[8];
    const float* bo   = (const float*)d_in[9];
    const float* erk  = (const float*)d_in[10];
    const float* erv  = (const float*)d_in[11];
    const float* ln1g = (const float*)d_in[12];
    const float* ln1b = (const float*)d_in[13];
    const float* w1   = (const float*)d_in[14];
    const float* b1   = (const float*)d_in[15];
    const float* w2   = (const float*)d_in[16];
    const float* b2   = (const float*)d_in[17];
    const float* ln2g = (const float*)d_in[18];
    const float* ln2b = (const float*)d_in[19];

    const size_t N = (size_t)Bn * Cn * Tn;         // 1,572,864
    const int WC = Ln * Cn * Cn;                   // 221,184
    const size_t WF = (size_t)Ln * 3 * FCn * Cn;   // 2,654,208
    const size_t WQKV = (size_t)Ln * 576 * Cn;     // 663,552
    const size_t NSCR = (size_t)Bn * Tn * FCn;     // 6,291,456 == NSPLIT*RN*96

    float* X    = (float*)d_ws;
    float* Yb   = X + N;                           // conv_o out / FFN2 partial 0
    float* bqkv = Yb + N;                          // L*576 floats
    float* Mp   = bqkv + Ln * 576;                 // NSPLIT*RN floats
    float* Lp   = Mp + (size_t)NSPLIT * RN;
    bf16* p16 = (bf16*)(Lp + (size_t)NSPLIT * RN);
    bf16* XT   = p16; p16 += N;
    bf16* QKT  = p16; p16 += (size_t)Bn * Tn * QKS;  // 2N bf16; dead after attn
    bf16* Vb   = p16; p16 += N;
    bf16* AT   = p16; p16 += N;
    bf16* SCR  = p16; p16 += NSCR;   // shared: attn O-partials <-> FFN hidden
    bf16* Wqkv = p16; p16 += WQKV;
    bf16* Wob  = p16; p16 += WC;
    bf16* W1t  = p16; p16 += WF;
    bf16* W2t  = p16; p16 += WF;
    bf16* ERKB = p16; p16 += Ln * 16 * 96;
    float* P1  = (float*)QKT;        // FFN2 partial 1 aliases dead QKT (N fp32)

    const float qscale = 0.10206207261596575f;  // 1/sqrt(96)

    // one-time transforms
    qkv_prep<<<(int)((WQKV + Ln * 576 + 255) / 256), 256, 0, stream>>>(
        Wq, Wk, Wv, bq, bk, bv, Wqkv, bqkv, qscale);
    cast_bf<<<(WC + 255) / 256, 256, 0, stream>>>(Wo, Wob, WC);
    reorder_w<<<(int)((WF + 255) / 256), 256, 0, stream>>>(w1, W1t, FCn, Cn);
    reorder_w<<<(int)((WF + 255) / 256), 256, 0, stream>>>(w2, W2t, Cn, FCn);
    erk_prep<<<(Ln * 16 * 96 + 255) / 256, 256, 0, stream>>>(erk, ERKB);
    cvt_in_k<<<Bn * 32, 256, 0, stream>>>(x, mask, X, XT);

    for (int l = 0; l < Ln; ++l) {
        conv_mfma<1, 64, 4, 1><<<dim3(Tn / 64, 9, Bn), 256, 0, stream>>>(
            XT, Wqkv + (size_t)l * 576 * Cn, bqkv + l * 576, nullptr, QKT, Vb, Cn, 576);
        attn_mfma<<<dim3(Tn / 64, Hn, Bn * NSPLIT), 256, 0, stream>>>(
            QKT, Vb, mask, ERKB, erv, SCR, Mp, Lp, l);
        attn_combine<<<RN * 12 / 256, 256, 0, stream>>>(SCR, Mp, Lp, AT);
        conv_mfma<1, 32, 0, 1><<<dim3(Tn / 32, 3, Bn), 256, 0, stream>>>(
            AT, Wob + (size_t)l * Cn * Cn, bo + l * Cn, nullptr, Yb, nullptr, Cn, Cn);
        ln_k<<<Bn * 32, 256, 0, stream>>>(X, Yb, ln1g + l * Cn, ln1b + l * Cn, mask, XT, 1);
        conv_mfma<3, 64, 2, 1><<<dim3(Tn / 64, FCn / 64, Bn), 256, 0, stream>>>(
            XT, W1t + (size_t)l * 3 * FCn * Cn, b1 + l * FCn, mask, SCR, nullptr, Cn, FCn);
        conv_mfma<3, 64, 5, 2><<<dim3(Tn / 64, 3, Bn * 2), 256, 0, stream>>>(
            SCR, W2t + (size_t)l * 3 * Cn * FCn, b2 + l * Cn, mask, Yb, P1, FCn, Cn);
        ln_ffn2<<<Bn * 32, 256, 0, stream>>>(X, Yb, P1, b2 + l * Cn,
                                             ln2g + l * Cn, ln2b + l * Cn, mask, XT,
                                             (l == Ln - 1) ? (float*)d_out : nullptr);
    }
}

// Round 13
// 1141.382 us; speedup vs baseline: 1.6168x; 1.6168x over previous
//
#include <hip/hip_runtime.h>
#include <hip/hip_bf16.h>

// Problem constants
constexpr int Bn  = 8;
constexpr int Cn  = 192;   // hidden channels
constexpr int Tn  = 1024;  // sequence length
constexpr int Hn  = 2;     // heads
constexpr int DKn = 96;    // head dim
constexpr int FCn = 768;   // filter channels
constexpr int Ln  = 6;     // layers
constexpr int WINn = 4;    // rel-attn window
constexpr int QKS = 384;   // QK transposed row stride (Q|K concat)
constexpr int NSPLIT = 4;  // attention s-split (flash-decoding)
constexpr int RN  = Bn * Hn * Tn;  // 16384 attention rows

typedef __hip_bfloat16 bf16;
typedef __attribute__((ext_vector_type(8))) short short8;
typedef __attribute__((ext_vector_type(4))) float f32x4;

// ---------------------------------------------------------------------------
// One-time transforms
__global__ void cast_bf(const float* __restrict__ src, bf16* __restrict__ dst, int n) {
    int i = blockIdx.x * 256 + threadIdx.x;
    if (i < n) dst[i] = __float2bfloat16(src[i]);
}

// w [L][CO][CIN][3] -> [L][3][CO][CIN] bf16
__global__ void reorder_w(const float* __restrict__ src, bf16* __restrict__ dst,
                          int CO, int CIN) {
    int i = blockIdx.x * 256 + threadIdx.x;
    int n = Ln * 3 * CO * CIN;
    if (i >= n) return;
    int c = i % CIN;
    int f = (i / CIN) % CO;
    int ko = (i / (CIN * CO)) % 3;
    int l = i / (3 * CIN * CO);
    dst[i] = __float2bfloat16(src[(((size_t)(l * CO + f)) * CIN + c) * 3 + ko]);
}

// erk fp32 [L][9][96] -> bf16 [L][16][96], rows 9..15 zero (MFMA B-frag ready)
__global__ void erk_prep(const float* __restrict__ src, bf16* __restrict__ dst) {
    int i = blockIdx.x * 256 + threadIdx.x;       // < Ln*16*96
    if (i >= Ln * 16 * 96) return;
    int d = i % 96, row = (i / 96) % 16, l = i / (96 * 16);
    float v = (row < 9) ? src[((size_t)l * 9 + row) * 96 + d] : 0.f;
    dst[i] = __float2bfloat16(v);
}

// Build fused QKV weight [L][576][C] bf16 (qscale folded into Q) + bias fp32
__global__ void qkv_prep(const float* __restrict__ Wq, const float* __restrict__ Wk,
                         const float* __restrict__ Wv, const float* __restrict__ bq,
                         const float* __restrict__ bk, const float* __restrict__ bv,
                         bf16* __restrict__ Wout, float* __restrict__ bout, float qscale) {
    int i = blockIdx.x * 256 + threadIdx.x;
    const int nW = Ln * 576 * Cn;
    if (i < nW) {
        int c = i % Cn, f = (i / Cn) % 576, l = i / (Cn * 576);
        float v;
        if (f < 192)      v = Wq[((size_t)l * Cn + f) * Cn + c] * qscale;
        else if (f < 384) v = Wk[((size_t)l * Cn + f - 192) * Cn + c];
        else              v = Wv[((size_t)l * Cn + f - 384) * Cn + c];
        Wout[i] = __float2bfloat16(v);
    } else if (i < nW + Ln * 576) {
        int j = i - nW, f = j % 576, l = j / 576;
        float v;
        if (f < 192)      v = bq[l * Cn + f] * qscale;
        else if (f < 384) v = bk[l * Cn + f - 192];
        else              v = bv[l * Cn + f - 384];
        bout[j] = v;
    }
}

// ---------------------------------------------------------------------------
// Input: X = x*mask (fp32, NCT) + XT = bf16 transposed [b][t][c]
__global__ __launch_bounds__(256) void cvt_in_k(
        const float* __restrict__ x, const float* __restrict__ mask,
        float* __restrict__ X, bf16* __restrict__ XT) {
    __shared__ float tile[Cn][33];
    const int tid = threadIdx.x, lane = tid & 31, w = tid >> 5;
    const int b = blockIdx.x >> 5;
    const int t0 = (blockIdx.x & 31) * 32;
    const float mk = mask[b * Tn + t0 + lane];
    for (int c = w; c < Cn; c += 8) {
        float v = x[((b * Cn + c) * Tn) + t0 + lane] * mk;
        X[((b * Cn + c) * Tn) + t0 + lane] = v;
        tile[c][lane] = v;
    }
    __syncthreads();
    for (int idx = tid; idx < 32 * Cn; idx += 256) {
        int tl = idx / Cn, c = idx % Cn;
        XT[((size_t)b * Tn + t0 + tl) * Cn + c] = __float2bfloat16(tile[c][tl]);
    }
}

// ---------------------------------------------------------------------------
// MFMA conv1d, LDS-staged (m97 structure): the A-tile (TT+KS-1 rows, shared
// by all 4 waves) and B-tile (KS x 64 f-rows) are cooperatively staged into
// LDS with coalesced loads, fragments read via ds_read_b128 from 72-col
// padded rows (floor-rate banks). Single-buffered, 2 barriers per chunk.
// MODE 0: fp32 NCT out (+bias, *mask if mask!=null)
// MODE 2: bf16 transposed [b][t][CO] out relu(+bias)*mask   [FFN1]
// MODE 4: QKV split: f<384 -> bf16 T (stride QKS) into Y0; else bf16 NCT Y1
// MODE 5: fp32 NCT K-split partial, NO bias: ks==0 -> Y0, ks==1 -> Y1 [FFN2]
template <int KS, int TT, int MODE, int NSP>
__global__ __launch_bounds__(256) void conv_mfma(
        const bf16* __restrict__ Xt, const bf16* __restrict__ W,
        const float* __restrict__ bias, const float* __restrict__ mask,
        void* __restrict__ Y0, void* __restrict__ Y1, int CIN, int CO) {
    constexpr int PAD = KS / 2;
    constexpr int NMB = TT / 16;
    constexpr int AR  = TT + KS - 1;   // A rows staged
    constexpr int RS  = 72;            // padded row stride (bf16 cols)
    __shared__ bf16 As[AR][RS];
    __shared__ bf16 Bs[KS][64][RS];

    const int tid = threadIdx.x;
    const int wv = tid >> 6, lane = tid & 63;
    const int m = lane & 15, kq = lane >> 4;
    const int b = blockIdx.z / NSP, ks = blockIdx.z % NSP;
    const int t0 = blockIdx.x * TT;
    const int f0 = blockIdx.y * 64;
    const int f = f0 + wv * 16 + m;

    const bf16* xb = Xt + (size_t)b * Tn * CIN;
    const size_t wko = (size_t)CO * CIN;

    f32x4 acc[NMB] = {};

    const int cbeg = ks * (CIN / NSP);
    const int cend = cbeg + CIN / NSP;
    for (int c0 = cbeg; c0 < cend; c0 += 64) {
        __syncthreads();   // previous chunk's fragment reads complete
        // stage A: AR rows x 64 cols, zero at seq edges (KS3 only)
        for (int s = tid; s < AR * 8; s += 256) {
            int r = s >> 3, cs = (s & 7) * 8;
            int gt = t0 + r - PAD;
            short8 v = {0, 0, 0, 0, 0, 0, 0, 0};
            if (PAD == 0 || (unsigned)gt < (unsigned)Tn)
                v = *(const short8*)(xb + (size_t)gt * CIN + c0 + cs);
            *(short8*)&As[r][cs] = v;
        }
        // stage B: KS x 64 f-rows x 64 cols
        for (int s = tid; s < KS * 512; s += 256) {
            int ko = s >> 9, r = (s >> 3) & 63, cs = (s & 7) * 8;
            short8 v = *(const short8*)(W + (size_t)ko * wko + (size_t)(f0 + r) * CIN + c0 + cs);
            *(short8*)&Bs[ko][r][cs] = v;
        }
        __syncthreads();   // staged data visible
#pragma unroll
        for (int kk = 0; kk < 2; ++kk)
#pragma unroll
            for (int ko = 0; ko < KS; ++ko) {
                short8 bfr = *(const short8*)&Bs[ko][wv * 16 + m][kk * 32 + kq * 8];
#pragma unroll
                for (int mb = 0; mb < NMB; ++mb) {
                    short8 afr = *(const short8*)&As[mb * 16 + m + ko][kk * 32 + kq * 8];
                    acc[mb] = __builtin_amdgcn_mfma_f32_16x16x32_bf16(afr, bfr, acc[mb], 0, 0, 0);
                }
            }
    }

    if (MODE == 5) {
        float* Y = (float*)(ks ? Y1 : Y0) + ((size_t)b * CO + f) * Tn;
#pragma unroll
        for (int mb = 0; mb < NMB; ++mb) {
            int t = t0 + mb * 16 + kq * 4;
            float4 o;
            o.x = acc[mb][0]; o.y = acc[mb][1]; o.z = acc[mb][2]; o.w = acc[mb][3];
            *(float4*)(Y + t) = o;
        }
        return;
    }
    const float bs = bias[f];
    if (MODE == 0) {
        float* Y = (float*)Y0 + ((size_t)b * CO + f) * Tn;
#pragma unroll
        for (int mb = 0; mb < NMB; ++mb) {
            int t = t0 + mb * 16 + kq * 4;
            float4 o;
            o.x = acc[mb][0] + bs; o.y = acc[mb][1] + bs;
            o.z = acc[mb][2] + bs; o.w = acc[mb][3] + bs;
            if (mask) {
                o.x *= mask[b * Tn + t];     o.y *= mask[b * Tn + t + 1];
                o.z *= mask[b * Tn + t + 2]; o.w *= mask[b * Tn + t + 3];
            }
            *(float4*)(Y + t) = o;
        }
    } else if (MODE == 2) {
        bf16* Y = (bf16*)Y0;
#pragma unroll
        for (int mb = 0; mb < NMB; ++mb)
#pragma unroll
            for (int r = 0; r < 4; ++r) {
                int t = t0 + mb * 16 + kq * 4 + r;
                float v = fmaxf(acc[mb][r] + bs, 0.f) * mask[b * Tn + t];
                Y[((size_t)b * Tn + t) * CO + f] = __float2bfloat16(v);
            }
    } else {  // MODE 4
        if (blockIdx.y < 6) {          // Q|K -> transposed, stride QKS
            bf16* Y = (bf16*)Y0;
#pragma unroll
            for (int mb = 0; mb < NMB; ++mb)
#pragma unroll
                for (int r = 0; r < 4; ++r) {
                    int t = t0 + mb * 16 + kq * 4 + r;
                    Y[((size_t)b * Tn + t) * QKS + f] = __float2bfloat16(acc[mb][r] + bs);
                }
        } else {                        // V -> bf16 NCT
            bf16* Y = (bf16*)Y1 + ((size_t)b * Cn + f - 384) * Tn;
#pragma unroll
            for (int mb = 0; mb < NMB; ++mb) {
                int t = t0 + mb * 16 + kq * 4;
                bf16 tmp[4];
#pragma unroll
                for (int r = 0; r < 4; ++r) tmp[r] = __float2bfloat16(acc[mb][r] + bs);
                *(uint2*)(Y + t) = *(uint2*)tmp;
            }
        }
    }
}

// ---------------------------------------------------------------------------
// MFMA flash attention, split-K over s (R9 configuration — known best).
// QK: bf16 [b][t][384] (Q pre-scaled cols 0..191, K cols 192..383), V: bf16
// NCT, erkb: bf16 [L][16][96]. 256 thr = 4 waves, 16 q-rows/wave.
// Grid (T/64, H, B*NSPLIT). Barrier-free: all LDS per-wave.
// Writes UNNORMALIZED partials: Op bf16 [sp][rid][96], Mp/Lp fp32 [sp][rid].
__global__ __launch_bounds__(256) void attn_mfma(
        const bf16* __restrict__ QK, const bf16* __restrict__ V,
        const float* __restrict__ mask, const bf16* __restrict__ erkb,
        const float* __restrict__ erv, bf16* __restrict__ Op,
        float* __restrict__ Mp, float* __restrict__ Lp, int layer) {
    __shared__ float rq[4][16][17];   // per-wave rel-K band: [m][dd]
    __shared__ bf16 pT[4][16][72];    // per-wave P: [m][s]

    const int tid = threadIdx.x, wv = tid >> 6, lane = tid & 63;
    const int col = lane & 15, quad = lane >> 4;
    const int t0 = blockIdx.x * 64, h = blockIdx.y;
    const int b = blockIdx.z / NSPLIT, sp = blockIdx.z % NSPLIT;
    const int hd = h * DKn;
    const int t0w = t0 + wv * 16;

    // Q A-frags (persist): A[m=col][k=quad*8+j+32*kd]
    short8 aq[3];
    {
        const bf16* qrow = QK + ((size_t)b * Tn + t0w + col) * QKS + hd + quad * 8;
#pragma unroll
        for (int kd = 0; kd < 3; ++kd) aq[kd] = *(const short8*)(qrow + kd * 32);
    }
    // rel-K band via MFMA: R = Q . erk^T  (B rows 9..15 are zero)
    {
        const bf16* erow = erkb + ((size_t)layer * 16 + col) * 96 + quad * 8;
        f32x4 R = {};
#pragma unroll
        for (int kd = 0; kd < 3; ++kd) {
            short8 be = *(const short8*)(erow + kd * 32);
            R = __builtin_amdgcn_mfma_f32_16x16x32_bf16(aq[kd], be, R, 0, 0, 0);
        }
#pragma unroll
        for (int r = 0; r < 4; ++r) rq[wv][quad * 4 + r][col] = R[r];
    }
    float mtv[4];
#pragma unroll
    for (int r = 0; r < 4; ++r) mtv[r] = mask[b * Tn + t0w + quad * 4 + r];

    float mold[4] = {-3.0e38f, -3.0e38f, -3.0e38f, -3.0e38f};
    float lrow[4] = {};
    f32x4 O[6] = {};
    const float* ervl = erv + (size_t)layer * 9 * DKn;

    const int sbeg = sp * (Tn / NSPLIT);
    const int send = sbeg + Tn / NSPLIT;
    for (int s0 = sbeg; s0 < send; s0 += 64) {
        short8 bk[4][3];
#pragma unroll
        for (int nb = 0; nb < 4; ++nb) {
            const bf16* krow = QK + ((size_t)b * Tn + s0 + 16 * nb + col) * QKS + 192 + hd + quad * 8;
#pragma unroll
            for (int kd = 0; kd < 3; ++kd) bk[nb][kd] = *(const short8*)(krow + kd * 32);
        }
        short8 bv[6][2];
#pragma unroll
        for (int nd = 0; nd < 6; ++nd) {
            const bf16* vrow = V + ((size_t)(b * Cn + hd + 16 * nd + col)) * Tn + s0 + quad * 8;
#pragma unroll
            for (int kk = 0; kk < 2; ++kk) bv[nd][kk] = *(const short8*)(vrow + kk * 32);
        }

        f32x4 S[4] = {};
#pragma unroll
        for (int nb = 0; nb < 4; ++nb)
#pragma unroll
            for (int kd = 0; kd < 3; ++kd)
                S[nb] = __builtin_amdgcn_mfma_f32_16x16x32_bf16(aq[kd], bk[nb][kd], S[nb], 0, 0, 0);

#pragma unroll
        for (int nb = 0; nb < 4; ++nb) {
            const int sg = s0 + 16 * nb + col;
            const float msv = mask[b * Tn + sg];
#pragma unroll
            for (int r = 0; r < 4; ++r) {
                const int tq = t0w + quad * 4 + r;
                float v = S[nb][r];
                int dd = sg - tq + WINn;
                if (dd >= 0 && dd <= 2 * WINn) v += rq[wv][quad * 4 + r][dd];
                if (msv * mtv[r] == 0.f) v = -1e4f;
                S[nb][r] = v;
            }
        }

        float mnew[4], alpha[4], psum[4];
#pragma unroll
        for (int r = 0; r < 4; ++r) {
            float mc = fmaxf(fmaxf(S[0][r], S[1][r]), fmaxf(S[2][r], S[3][r]));
#pragma unroll
            for (int mk2 = 1; mk2 < 16; mk2 <<= 1) mc = fmaxf(mc, __shfl_xor(mc, mk2));
            mnew[r] = fmaxf(mold[r], mc);
            alpha[r] = (mold[r] <= -1.0e30f) ? 0.f : __expf(mold[r] - mnew[r]);
            mold[r] = mnew[r];
            psum[r] = 0.f;
        }
#pragma unroll
        for (int nb = 0; nb < 4; ++nb)
#pragma unroll
            for (int r = 0; r < 4; ++r) {
                bf16 pb = __float2bfloat16(__expf(S[nb][r] - mnew[r]));
                pT[wv][quad * 4 + r][16 * nb + col] = pb;
                psum[r] += __bfloat162float(pb);
            }
#pragma unroll
        for (int r = 0; r < 4; ++r) {
#pragma unroll
            for (int mk2 = 1; mk2 < 16; mk2 <<= 1) psum[r] += __shfl_xor(psum[r], mk2);
            lrow[r] = lrow[r] * alpha[r] + psum[r];
#pragma unroll
            for (int nd = 0; nd < 6; ++nd) O[nd][r] *= alpha[r];
        }

        short8 aP[2];
#pragma unroll
        for (int kk = 0; kk < 2; ++kk)
            aP[kk] = *(const short8*)&pT[wv][col][kk * 32 + quad * 8];
#pragma unroll
        for (int nd = 0; nd < 6; ++nd)
#pragma unroll
            for (int kk = 0; kk < 2; ++kk)
                O[nd] = __builtin_amdgcn_mfma_f32_16x16x32_bf16(aP[kk], bv[nd][kk], O[nd], 0, 0, 0);

        if (s0 <= t0w + 15 + WINn && s0 + 63 >= t0w - WINn) {
#pragma unroll
            for (int r = 0; r < 4; ++r) {
                const int tq = t0w + quad * 4 + r;
                for (int dd = 0; dd <= 2 * WINn; ++dd) {
                    int sg = tq + dd - WINn;
                    if (sg >= s0 && sg < s0 + 64) {
                        float p = __bfloat162float(pT[wv][quad * 4 + r][sg - s0]);
#pragma unroll
                        for (int nd = 0; nd < 6; ++nd)
                            O[nd][r] += p * ervl[dd * DKn + 16 * nd + col];
                    }
                }
            }
        }
    }

    // epilogue: write unnormalized partials
    const int rbase = (b * Hn + h) * Tn + t0w;
#pragma unroll
    for (int r = 0; r < 4; ++r) {
        const int rid = rbase + quad * 4 + r;
        bf16* dst = Op + ((size_t)sp * RN + rid) * 96 + col;
#pragma unroll
        for (int nd = 0; nd < 6; ++nd)
            dst[16 * nd] = __float2bfloat16(O[nd][r]);
        if (col == 0) {
            Mp[sp * RN + rid] = mold[r];
            Lp[sp * RN + rid] = lrow[r];
        }
    }
}

// Combine split partials -> AT bf16 [b][t][C]. One thread per (rid, 8-chan).
__global__ __launch_bounds__(256) void attn_combine(
        const bf16* __restrict__ Op, const float* __restrict__ Mp,
        const float* __restrict__ Lp, bf16* __restrict__ AT) {
    int i = blockIdx.x * 256 + threadIdx.x;       // < RN*12
    int rid = i / 12, j = i - rid * 12;
    float m[NSPLIT], l[NSPLIT], mx = -3.0e38f;
#pragma unroll
    for (int s = 0; s < NSPLIT; ++s) {
        m[s] = Mp[s * RN + rid];
        l[s] = Lp[s * RN + rid];
        mx = fmaxf(mx, m[s]);
    }
    float denom = 0.f;
    float o[8] = {};
#pragma unroll
    for (int s = 0; s < NSPLIT; ++s) {
        float sc = __expf(m[s] - mx);
        denom += sc * l[s];
        short8 v = *(const short8*)(Op + ((size_t)s * RN + rid) * 96 + j * 8);
        const bf16* vb = (const bf16*)&v;
#pragma unroll
        for (int e = 0; e < 8; ++e) o[e] += sc * __bfloat162float(vb[e]);
    }
    float inv = 1.f / denom;
    int t = rid & (Tn - 1), h = (rid >> 10) & (Hn - 1), b = rid >> 11;
    bf16 outv[8];
#pragma unroll
    for (int e = 0; e < 8; ++e) outv[e] = __float2bfloat16(o[e] * inv);
    *(uint4*)(AT + ((size_t)b * Tn + t) * Cn + h * DKn + j * 8) = *(uint4*)outv;
}

// ---------------------------------------------------------------------------
// Residual add + LayerNorm over channels. X <- LN(X+Y)*g+b (fp32) and
// XT <- bf16 transposed [b][t][C], optionally *mask.
__global__ __launch_bounds__(256) void ln_k(
        float* __restrict__ X, const float* __restrict__ Y,
        const float* __restrict__ G, const float* __restrict__ Bt,
        const float* __restrict__ mask, bf16* __restrict__ XT, int apply_mask) {
    __shared__ float tile[Cn][33];
    __shared__ float r1[8][32];
    __shared__ float r2[8][32];
    const int tid = threadIdx.x;
    const int lane = tid & 31, w = tid >> 5;
    const int b = blockIdx.x >> 5;
    const int t0 = (blockIdx.x & 31) * 32;
    const int t = t0 + lane;

    float s1 = 0.f, s2 = 0.f;
    for (int c = w; c < Cn; c += 8) {
        float v = X[((b * Cn + c) * Tn) + t] + Y[((b * Cn + c) * Tn) + t];
        tile[c][lane] = v;
        s1 += v;
        s2 += v * v;
    }
    r1[w][lane] = s1;
    r2[w][lane] = s2;
    __syncthreads();
    if (w == 0) {
        float a = 0.f, q = 0.f;
        for (int i = 0; i < 8; ++i) { a += r1[i][lane]; q += r2[i][lane]; }
        float m = a / Cn;
        float var = q / Cn - m * m;
        r1[0][lane] = m;
        r2[0][lane] = rsqrtf(var + 1e-5f);
    }
    __syncthreads();
    const float m = r1[0][lane], rs = r2[0][lane];
    for (int c = w; c < Cn; c += 8) {
        float y = (tile[c][lane] - m) * rs * G[c] + Bt[c];
        X[((b * Cn + c) * Tn) + t] = y;
        tile[c][lane] = y;
    }
    __syncthreads();
    for (int idx = tid; idx < 32 * Cn; idx += 256) {
        int tl = idx / Cn, c = idx % Cn;
        float v = tile[c][tl];
        if (apply_mask) v *= mask[b * Tn + t0 + tl];
        XT[((size_t)b * Tn + t0 + tl) * Cn + c] = __float2bfloat16(v);
    }
}

// FFN2-combine + residual + LN2: Y = (P0+P1+bias)*mask; Xn = LN(X+Y)*g+b.
// OUT==null: X <- Xn, XT <- bf16(Xn).  OUT!=null (last layer): OUT <- Xn*mask.
__global__ __launch_bounds__(256) void ln_ffn2(
        float* __restrict__ X, const float* __restrict__ P0,
        const float* __restrict__ P1, const float* __restrict__ bias,
        const float* __restrict__ G, const float* __restrict__ Bt,
        const float* __restrict__ mask, bf16* __restrict__ XT,
        float* __restrict__ OUT) {
    __shared__ float tile[Cn][33];
    __shared__ float r1[8][32];
    __shared__ float r2[8][32];
    const int tid = threadIdx.x;
    const int lane = tid & 31, w = tid >> 5;
    const int b = blockIdx.x >> 5;
    const int t0 = (blockIdx.x & 31) * 32;
    const int t = t0 + lane;
    const float mk = mask[b * Tn + t];

    float s1 = 0.f, s2 = 0.f;
    for (int c = w; c < Cn; c += 8) {
        size_t i = ((size_t)b * Cn + c) * Tn + t;
        float y = (P0[i] + P1[i] + bias[c]) * mk;
        float v = X[i] + y;
        tile[c][lane] = v;
        s1 += v;
        s2 += v * v;
    }
    r1[w][lane] = s1;
    r2[w][lane] = s2;
    __syncthreads();
    if (w == 0) {
        float a = 0.f, q = 0.f;
        for (int i = 0; i < 8; ++i) { a += r1[i][lane]; q += r2[i][lane]; }
        float m = a / Cn;
        float var = q / Cn - m * m;
        r1[0][lane] = m;
        r2[0][lane] = rsqrtf(var + 1e-5f);
    }
    __syncthreads();
    const float m = r1[0][lane], rs = r2[0][lane];
    if (OUT) {   // final layer: write output = LN(...)*mask directly, done
        for (int c = w; c < Cn; c += 8) {
            float y = (tile[c][lane] - m) * rs * G[c] + Bt[c];
            OUT[((b * Cn + c) * Tn) + t] = y * mk;
        }
        return;
    }
    for (int c = w; c < Cn; c += 8) {
        float y = (tile[c][lane] - m) * rs * G[c] + Bt[c];
        X[((b * Cn + c) * Tn) + t] = y;
        tile[c][lane] = y;
    }
    __syncthreads();
    for (int idx = tid; idx < 32 * Cn; idx += 256) {
        int tl = idx / Cn, c = idx % Cn;
        XT[((size_t)b * Tn + t0 + tl) * Cn + c] = __float2bfloat16(tile[c][tl]);
    }
}

// ---------------------------------------------------------------------------
extern "C" void kernel_launch(void* const* d_in, const int* in_sizes, int n_in,
                              void* d_out, int out_size, void* d_ws, size_t ws_size,
                              hipStream_t stream) {
    const float* x    = (const float*)d_in[0];
    const float* mask = (const float*)d_in[1];
    const float* Wq   = (const float*)d_in[2];
    const float* bq   = (const float*)d_in[3];
    const float* Wk   = (const float*)d_in[4];
    const float* bk   = (const float*)d_in[5];
    const float* Wv   = (const float*)d_in[6];
    const float* bv   = (const float*)d_in[7];
    const float* Wo   = (const float*)d_in[8];
    const float* bo   = (const float*)d_in[9];
    const float* erk  = (const float*)d_in[10];
    const float* erv  = (const float*)d_in[11];
    const float* ln1g = (const float*)d_in[12];
    const float* ln1b = (const float*)d_in[13];
    const float* w1   = (const float*)d_in[14];
    const float* b1   = (const float*)d_in[15];
    const float* w2   = (const float*)d_in[16];
    const float* b2   = (const float*)d_in[17];
    const float* ln2g = (const float*)d_in[18];
    const float* ln2b = (const float*)d_in[19];

    const size_t N = (size_t)Bn * Cn * Tn;         // 1,572,864
    const int WC = Ln * Cn * Cn;                   // 221,184
    const size_t WF = (size_t)Ln * 3 * FCn * Cn;   // 2,654,208
    const size_t WQKV = (size_t)Ln * 576 * Cn;     // 663,552
    const size_t NSCR = (size_t)Bn * Tn * FCn;     // 6,291,456 == NSPLIT*RN*96

    float* X    = (float*)d_ws;
    float* Yb   = X + N;                           // conv_o out / FFN2 partial 0
    float* bqkv = Yb + N;                          // L*576 floats
    float* Mp   = bqkv + Ln * 576;                 // NSPLIT*RN floats
    float* Lp   = Mp + (size_t)NSPLIT * RN;
    bf16* p16 = (bf16*)(Lp + (size_t)NSPLIT * RN);
    bf16* XT   = p16; p16 += N;
    bf16* QKT  = p16; p16 += (size_t)Bn * Tn * QKS;  // 2N bf16; dead after attn
    bf16* Vb   = p16; p16 += N;
    bf16* AT   = p16; p16 += N;
    bf16* SCR  = p16; p16 += NSCR;   // shared: attn O-partials <-> FFN hidden
    bf16* Wqkv = p16; p16 += WQKV;
    bf16* Wob  = p16; p16 += WC;
    bf16* W1t  = p16; p16 += WF;
    bf16* W2t  = p16; p16 += WF;
    bf16* ERKB = p16; p16 += Ln * 16 * 96;
    float* P1  = (float*)QKT;        // FFN2 partial 1 aliases dead QKT (N fp32)

    const float qscale = 0.10206207261596575f;  // 1/sqrt(96)

    // one-time transforms
    qkv_prep<<<(int)((WQKV + Ln * 576 + 255) / 256), 256, 0, stream>>>(
        Wq, Wk, Wv, bq, bk, bv, Wqkv, bqkv, qscale);
    cast_bf<<<(WC + 255) / 256, 256, 0, stream>>>(Wo, Wob, WC);
    reorder_w<<<(int)((WF + 255) / 256), 256, 0, stream>>>(w1, W1t, FCn, Cn);
    reorder_w<<<(int)((WF + 255) / 256), 256, 0, stream>>>(w2, W2t, Cn, FCn);
    erk_prep<<<(Ln * 16 * 96 + 255) / 256, 256, 0, stream>>>(erk, ERKB);
    cvt_in_k<<<Bn * 32, 256, 0, stream>>>(x, mask, X, XT);

    for (int l = 0; l < Ln; ++l) {
        conv_mfma<1, 64, 4, 1><<<dim3(Tn / 64, 9, Bn), 256, 0, stream>>>(
            XT, Wqkv + (size_t)l * 576 * Cn, bqkv + l * 576, nullptr, QKT, Vb, Cn, 576);
        attn_mfma<<<dim3(Tn / 64, Hn, Bn * NSPLIT), 256, 0, stream>>>(
            QKT, Vb, mask, ERKB, erv, SCR, Mp, Lp, l);
        attn_combine<<<RN * 12 / 256, 256, 0, stream>>>(SCR, Mp, Lp, AT);
        conv_mfma<1, 32, 0, 1><<<dim3(Tn / 32, 3, Bn), 256, 0, stream>>>(
            AT, Wob + (size_t)l * Cn * Cn, bo + l * Cn, nullptr, Yb, nullptr, Cn, Cn);
        ln_k<<<Bn * 32, 256, 0, stream>>>(X, Yb, ln1g + l * Cn, ln1b + l * Cn, mask, XT, 1);
        conv_mfma<3, 64, 2, 1><<<dim3(Tn / 64, FCn / 64, Bn), 256, 0, stream>>>(
            XT, W1t + (size_t)l * 3 * FCn * Cn, b1 + l * FCn, mask, SCR, nullptr, Cn, FCn);
        conv_mfma<3, 64, 5, 2><<<dim3(Tn / 64, 3, Bn * 2), 256, 0, stream>>>(
            SCR, W2t + (size_t)l * 3 * Cn * FCn, b2 + l * Cn, mask, Yb, P1, FCn, Cn);
        ln_ffn2<<<Bn * 32, 256, 0, stream>>>(X, Yb, P1, b2 + l * Cn,
                                             ln2g + l * Cn, ln2b + l * Cn, mask, XT,
                                             (l == Ln - 1) ? (float*)d_out : nullptr);
    }
}

// Round 14
// 1019.265 us; speedup vs baseline: 1.8105x; 1.1198x over previous
//
#include <hip/hip_runtime.h>
#include <hip/hip_bf16.h>

// Problem constants
constexpr int Bn  = 8;
constexpr int Cn  = 192;   // hidden channels
constexpr int Tn  = 1024;  // sequence length
constexpr int Hn  = 2;     // heads
constexpr int DKn = 96;    // head dim
constexpr int FCn = 768;   // filter channels
constexpr int Ln  = 6;     // layers
constexpr int WINn = 4;    // rel-attn window
constexpr int QKS = 384;   // QK transposed row stride (Q|K concat)
constexpr int NSPLIT = 4;  // attention s-split (flash-decoding)
constexpr int RN  = Bn * Hn * Tn;  // 16384 attention rows

typedef __hip_bfloat16 bf16;
typedef __attribute__((ext_vector_type(8))) short short8;
typedef __attribute__((ext_vector_type(4))) float f32x4;

// ---------------------------------------------------------------------------
// One-time transforms
__global__ void cast_bf(const float* __restrict__ src, bf16* __restrict__ dst, int n) {
    int i = blockIdx.x * 256 + threadIdx.x;
    if (i < n) dst[i] = __float2bfloat16(src[i]);
}

// w [L][CO][CIN][3] -> [L][3][CO][CIN] bf16
__global__ void reorder_w(const float* __restrict__ src, bf16* __restrict__ dst,
                          int CO, int CIN) {
    int i = blockIdx.x * 256 + threadIdx.x;
    int n = Ln * 3 * CO * CIN;
    if (i >= n) return;
    int c = i % CIN;
    int f = (i / CIN) % CO;
    int ko = (i / (CIN * CO)) % 3;
    int l = i / (3 * CIN * CO);
    dst[i] = __float2bfloat16(src[(((size_t)(l * CO + f)) * CIN + c) * 3 + ko]);
}

// erk fp32 [L][9][96] -> bf16 [L][16][96], rows 9..15 zero (MFMA B-frag ready)
__global__ void erk_prep(const float* __restrict__ src, bf16* __restrict__ dst) {
    int i = blockIdx.x * 256 + threadIdx.x;       // < Ln*16*96
    if (i >= Ln * 16 * 96) return;
    int d = i % 96, row = (i / 96) % 16, l = i / (96 * 16);
    float v = (row < 9) ? src[((size_t)l * 9 + row) * 96 + d] : 0.f;
    dst[i] = __float2bfloat16(v);
}

// Build fused QKV weight [L][576][C] bf16 (qscale folded into Q) + bias fp32
__global__ void qkv_prep(const float* __restrict__ Wq, const float* __restrict__ Wk,
                         const float* __restrict__ Wv, const float* __restrict__ bq,
                         const float* __restrict__ bk, const float* __restrict__ bv,
                         bf16* __restrict__ Wout, float* __restrict__ bout, float qscale) {
    int i = blockIdx.x * 256 + threadIdx.x;
    const int nW = Ln * 576 * Cn;
    if (i < nW) {
        int c = i % Cn, f = (i / Cn) % 576, l = i / (Cn * 576);
        float v;
        if (f < 192)      v = Wq[((size_t)l * Cn + f) * Cn + c] * qscale;
        else if (f < 384) v = Wk[((size_t)l * Cn + f - 192) * Cn + c];
        else              v = Wv[((size_t)l * Cn + f - 384) * Cn + c];
        Wout[i] = __float2bfloat16(v);
    } else if (i < nW + Ln * 576) {
        int j = i - nW, f = j % 576, l = j / 576;
        float v;
        if (f < 192)      v = bq[l * Cn + f] * qscale;
        else if (f < 384) v = bk[l * Cn + f - 192];
        else              v = bv[l * Cn + f - 384];
        bout[j] = v;
    }
}

// ---------------------------------------------------------------------------
// Input: X = x*mask (fp32, NCT) + XT = bf16 transposed [b][t][c]
__global__ __launch_bounds__(256) void cvt_in_k(
        const float* __restrict__ x, const float* __restrict__ mask,
        float* __restrict__ X, bf16* __restrict__ XT) {
    __shared__ float tile[Cn][33];
    const int tid = threadIdx.x, lane = tid & 31, w = tid >> 5;
    const int b = blockIdx.x >> 5;
    const int t0 = (blockIdx.x & 31) * 32;
    const float mk = mask[b * Tn + t0 + lane];
    for (int c = w; c < Cn; c += 8) {
        float v = x[((b * Cn + c) * Tn) + t0 + lane] * mk;
        X[((b * Cn + c) * Tn) + t0 + lane] = v;
        tile[c][lane] = v;
    }
    __syncthreads();
    for (int idx = tid; idx < 32 * Cn; idx += 256) {
        int tl = idx / Cn, c = idx % Cn;
        XT[((size_t)b * Tn + t0 + tl) * Cn + c] = __float2bfloat16(tile[c][tl]);
    }
}

// ---------------------------------------------------------------------------
// MFMA conv1d, LDS-staged (m97 structure) — R12 winner, unchanged.
// MODE 0: fp32 NCT out (+bias, *mask if mask!=null)
// MODE 2: bf16 transposed [b][t][CO] out relu(+bias)*mask   [FFN1]
// MODE 4: QKV split: f<384 -> bf16 T (stride QKS) into Y0; else bf16 NCT Y1
// MODE 5: fp32 NCT K-split partial, NO bias: ks==0 -> Y0, ks==1 -> Y1 [FFN2]
template <int KS, int TT, int MODE, int NSP>
__global__ __launch_bounds__(256) void conv_mfma(
        const bf16* __restrict__ Xt, const bf16* __restrict__ W,
        const float* __restrict__ bias, const float* __restrict__ mask,
        void* __restrict__ Y0, void* __restrict__ Y1, int CIN, int CO) {
    constexpr int PAD = KS / 2;
    constexpr int NMB = TT / 16;
    constexpr int AR  = TT + KS - 1;   // A rows staged
    constexpr int RS  = 72;            // padded row stride (bf16 cols)
    __shared__ bf16 As[AR][RS];
    __shared__ bf16 Bs[KS][64][RS];

    const int tid = threadIdx.x;
    const int wv = tid >> 6, lane = tid & 63;
    const int m = lane & 15, kq = lane >> 4;
    const int b = blockIdx.z / NSP, ks = blockIdx.z % NSP;
    const int t0 = blockIdx.x * TT;
    const int f0 = blockIdx.y * 64;
    const int f = f0 + wv * 16 + m;

    const bf16* xb = Xt + (size_t)b * Tn * CIN;
    const size_t wko = (size_t)CO * CIN;

    f32x4 acc[NMB] = {};

    const int cbeg = ks * (CIN / NSP);
    const int cend = cbeg + CIN / NSP;
    for (int c0 = cbeg; c0 < cend; c0 += 64) {
        __syncthreads();   // previous chunk's fragment reads complete
        for (int s = tid; s < AR * 8; s += 256) {
            int r = s >> 3, cs = (s & 7) * 8;
            int gt = t0 + r - PAD;
            short8 v = {0, 0, 0, 0, 0, 0, 0, 0};
            if (PAD == 0 || (unsigned)gt < (unsigned)Tn)
                v = *(const short8*)(xb + (size_t)gt * CIN + c0 + cs);
            *(short8*)&As[r][cs] = v;
        }
        for (int s = tid; s < KS * 512; s += 256) {
            int ko = s >> 9, r = (s >> 3) & 63, cs = (s & 7) * 8;
            short8 v = *(const short8*)(W + (size_t)ko * wko + (size_t)(f0 + r) * CIN + c0 + cs);
            *(short8*)&Bs[ko][r][cs] = v;
        }
        __syncthreads();   // staged data visible
#pragma unroll
        for (int kk = 0; kk < 2; ++kk)
#pragma unroll
            for (int ko = 0; ko < KS; ++ko) {
                short8 bfr = *(const short8*)&Bs[ko][wv * 16 + m][kk * 32 + kq * 8];
#pragma unroll
                for (int mb = 0; mb < NMB; ++mb) {
                    short8 afr = *(const short8*)&As[mb * 16 + m + ko][kk * 32 + kq * 8];
                    acc[mb] = __builtin_amdgcn_mfma_f32_16x16x32_bf16(afr, bfr, acc[mb], 0, 0, 0);
                }
            }
    }

    if (MODE == 5) {
        float* Y = (float*)(ks ? Y1 : Y0) + ((size_t)b * CO + f) * Tn;
#pragma unroll
        for (int mb = 0; mb < NMB; ++mb) {
            int t = t0 + mb * 16 + kq * 4;
            float4 o;
            o.x = acc[mb][0]; o.y = acc[mb][1]; o.z = acc[mb][2]; o.w = acc[mb][3];
            *(float4*)(Y + t) = o;
        }
        return;
    }
    const float bs = bias[f];
    if (MODE == 0) {
        float* Y = (float*)Y0 + ((size_t)b * CO + f) * Tn;
#pragma unroll
        for (int mb = 0; mb < NMB; ++mb) {
            int t = t0 + mb * 16 + kq * 4;
            float4 o;
            o.x = acc[mb][0] + bs; o.y = acc[mb][1] + bs;
            o.z = acc[mb][2] + bs; o.w = acc[mb][3] + bs;
            if (mask) {
                o.x *= mask[b * Tn + t];     o.y *= mask[b * Tn + t + 1];
                o.z *= mask[b * Tn + t + 2]; o.w *= mask[b * Tn + t + 3];
            }
            *(float4*)(Y + t) = o;
        }
    } else if (MODE == 2) {
        bf16* Y = (bf16*)Y0;
#pragma unroll
        for (int mb = 0; mb < NMB; ++mb)
#pragma unroll
            for (int r = 0; r < 4; ++r) {
                int t = t0 + mb * 16 + kq * 4 + r;
                float v = fmaxf(acc[mb][r] + bs, 0.f) * mask[b * Tn + t];
                Y[((size_t)b * Tn + t) * CO + f] = __float2bfloat16(v);
            }
    } else {  // MODE 4
        if (blockIdx.y < 6) {          // Q|K -> transposed, stride QKS
            bf16* Y = (bf16*)Y0;
#pragma unroll
            for (int mb = 0; mb < NMB; ++mb)
#pragma unroll
                for (int r = 0; r < 4; ++r) {
                    int t = t0 + mb * 16 + kq * 4 + r;
                    Y[((size_t)b * Tn + t) * QKS + f] = __float2bfloat16(acc[mb][r] + bs);
                }
        } else {                        // V -> bf16 NCT
            bf16* Y = (bf16*)Y1 + ((size_t)b * Cn + f - 384) * Tn;
#pragma unroll
            for (int mb = 0; mb < NMB; ++mb) {
                int t = t0 + mb * 16 + kq * 4;
                bf16 tmp[4];
#pragma unroll
                for (int r = 0; r < 4; ++r) tmp[r] = __float2bfloat16(acc[mb][r] + bs);
                *(uint2*)(Y + t) = *(uint2*)tmp;
            }
        }
    }
}

// ---------------------------------------------------------------------------
// MFMA flash attention, split-K over s, LDS-staged K/V (conv-style).
// K chunk (64 s-rows x 96 d) and V chunk (96 d-rows x 64 s) are cooperatively
// staged into padded LDS once per chunk (shared by all 4 waves -> 4x dedup,
// coalesced loads); fragments come from ds_read_b128. 2 barriers per chunk.
// QK: bf16 [b][t][384] (Q pre-scaled cols 0..191, K cols 192..383), V: bf16
// NCT, erkb: bf16 [L][16][96]. 256 thr = 4 waves, 16 q-rows/wave.
// Grid (T/64, H, B*NSPLIT) = 1024 blocks = 4/CU (LDS 40KB -> full residency).
// Writes UNNORMALIZED partials: Op bf16 [sp][rid][96], Mp/Lp fp32 [sp][rid].
__global__ __launch_bounds__(256) void attn_mfma(
        const bf16* __restrict__ QK, const bf16* __restrict__ V,
        const float* __restrict__ mask, const bf16* __restrict__ erkb,
        const float* __restrict__ erv, bf16* __restrict__ Op,
        float* __restrict__ Mp, float* __restrict__ Lp, int layer) {
    __shared__ bf16 Ks[64][104];      // K chunk [s][d] (pad 104: 2-way max)
    __shared__ bf16 Vs[96][72];       // V chunk [d][s] (pad 72)
    __shared__ float rq[4][16][17];   // per-wave rel-K band: [m][dd]
    __shared__ bf16 pT[4][16][72];    // per-wave P: [m][s]

    const int tid = threadIdx.x, wv = tid >> 6, lane = tid & 63;
    const int col = lane & 15, quad = lane >> 4;
    const int t0 = blockIdx.x * 64, h = blockIdx.y;
    const int b = blockIdx.z / NSPLIT, sp = blockIdx.z % NSPLIT;
    const int hd = h * DKn;
    const int t0w = t0 + wv * 16;

    // Q A-frags (persist): A[m=col][k=quad*8+j+32*kd]
    short8 aq[3];
    {
        const bf16* qrow = QK + ((size_t)b * Tn + t0w + col) * QKS + hd + quad * 8;
#pragma unroll
        for (int kd = 0; kd < 3; ++kd) aq[kd] = *(const short8*)(qrow + kd * 32);
    }
    // rel-K band via MFMA: R = Q . erk^T  (B rows 9..15 are zero)
    {
        const bf16* erow = erkb + ((size_t)layer * 16 + col) * 96 + quad * 8;
        f32x4 R = {};
#pragma unroll
        for (int kd = 0; kd < 3; ++kd) {
            short8 be = *(const short8*)(erow + kd * 32);
            R = __builtin_amdgcn_mfma_f32_16x16x32_bf16(aq[kd], be, R, 0, 0, 0);
        }
#pragma unroll
        for (int r = 0; r < 4; ++r) rq[wv][quad * 4 + r][col] = R[r];
    }
    float mtv[4];
#pragma unroll
    for (int r = 0; r < 4; ++r) mtv[r] = mask[b * Tn + t0w + quad * 4 + r];

    float mold[4] = {-3.0e38f, -3.0e38f, -3.0e38f, -3.0e38f};
    float lrow[4] = {};
    f32x4 O[6] = {};
    const float* ervl = erv + (size_t)layer * 9 * DKn;

    const int sbeg = sp * (Tn / NSPLIT);
    const int send = sbeg + Tn / NSPLIT;
    for (int s0 = sbeg; s0 < send; s0 += 64) {
        __syncthreads();   // previous chunk's Ks/Vs reads complete
        // stage K: 64 rows (s) x 96 cols (d), 12 short8/row, coalesced
        for (int s = tid; s < 768; s += 256) {
            int r = s / 12, cs = (s % 12) * 8;
            *(short8*)&Ks[r][cs] =
                *(const short8*)(QK + ((size_t)b * Tn + s0 + r) * QKS + 192 + hd + cs);
        }
        // stage V: 96 rows (d) x 64 cols (s), 8 short8/row, coalesced
        for (int s = tid; s < 768; s += 256) {
            int r = s >> 3, cs = (s & 7) * 8;
            *(short8*)&Vs[r][cs] =
                *(const short8*)(V + ((size_t)(b * Cn + hd + r)) * Tn + s0 + cs);
        }
        __syncthreads();   // staged data visible

        // S = Q K^T (B-frags from LDS)
        f32x4 S[4] = {};
#pragma unroll
        for (int nb = 0; nb < 4; ++nb)
#pragma unroll
            for (int kd = 0; kd < 3; ++kd) {
                short8 bkf = *(const short8*)&Ks[16 * nb + col][kd * 32 + quad * 8];
                S[nb] = __builtin_amdgcn_mfma_f32_16x16x32_bf16(aq[kd], bkf, S[nb], 0, 0, 0);
            }

#pragma unroll
        for (int nb = 0; nb < 4; ++nb) {
            const int sg = s0 + 16 * nb + col;
            const float msv = mask[b * Tn + sg];
#pragma unroll
            for (int r = 0; r < 4; ++r) {
                const int tq = t0w + quad * 4 + r;
                float v = S[nb][r];
                int dd = sg - tq + WINn;
                if (dd >= 0 && dd <= 2 * WINn) v += rq[wv][quad * 4 + r][dd];
                if (msv * mtv[r] == 0.f) v = -1e4f;
                S[nb][r] = v;
            }
        }

        // online softmax (16-lane shuffle reductions)
        float mnew[4], alpha[4], psum[4];
#pragma unroll
        for (int r = 0; r < 4; ++r) {
            float mc = fmaxf(fmaxf(S[0][r], S[1][r]), fmaxf(S[2][r], S[3][r]));
#pragma unroll
            for (int mk2 = 1; mk2 < 16; mk2 <<= 1) mc = fmaxf(mc, __shfl_xor(mc, mk2));
            mnew[r] = fmaxf(mold[r], mc);
            alpha[r] = (mold[r] <= -1.0e30f) ? 0.f : __expf(mold[r] - mnew[r]);
            mold[r] = mnew[r];
            psum[r] = 0.f;
        }
#pragma unroll
        for (int nb = 0; nb < 4; ++nb)
#pragma unroll
            for (int r = 0; r < 4; ++r) {
                bf16 pb = __float2bfloat16(__expf(S[nb][r] - mnew[r]));
                pT[wv][quad * 4 + r][16 * nb + col] = pb;
                psum[r] += __bfloat162float(pb);
            }
#pragma unroll
        for (int r = 0; r < 4; ++r) {
#pragma unroll
            for (int mk2 = 1; mk2 < 16; mk2 <<= 1) psum[r] += __shfl_xor(psum[r], mk2);
            lrow[r] = lrow[r] * alpha[r] + psum[r];
#pragma unroll
            for (int nd = 0; nd < 6; ++nd) O[nd][r] *= alpha[r];
        }

        // P A-frags from per-wave LDS; PV (V B-frags from shared LDS)
        short8 aP[2];
#pragma unroll
        for (int kk = 0; kk < 2; ++kk)
            aP[kk] = *(const short8*)&pT[wv][col][kk * 32 + quad * 8];
#pragma unroll
        for (int nd = 0; nd < 6; ++nd)
#pragma unroll
            for (int kk = 0; kk < 2; ++kk) {
                short8 bvf = *(const short8*)&Vs[16 * nd + col][kk * 32 + quad * 8];
                O[nd] = __builtin_amdgcn_mfma_f32_16x16x32_bf16(aP[kk], bvf, O[nd], 0, 0, 0);
            }

        // rel-V on diagonal chunks
        if (s0 <= t0w + 15 + WINn && s0 + 63 >= t0w - WINn) {
#pragma unroll
            for (int r = 0; r < 4; ++r) {
                const int tq = t0w + quad * 4 + r;
                for (int dd = 0; dd <= 2 * WINn; ++dd) {
                    int sg = tq + dd - WINn;
                    if (sg >= s0 && sg < s0 + 64) {
                        float p = __bfloat162float(pT[wv][quad * 4 + r][sg - s0]);
#pragma unroll
                        for (int nd = 0; nd < 6; ++nd)
                            O[nd][r] += p * ervl[dd * DKn + 16 * nd + col];
                    }
                }
            }
        }
    }

    // epilogue: write unnormalized partials
    const int rbase = (b * Hn + h) * Tn + t0w;
#pragma unroll
    for (int r = 0; r < 4; ++r) {
        const int rid = rbase + quad * 4 + r;
        bf16* dst = Op + ((size_t)sp * RN + rid) * 96 + col;
#pragma unroll
        for (int nd = 0; nd < 6; ++nd)
            dst[16 * nd] = __float2bfloat16(O[nd][r]);
        if (col == 0) {
            Mp[sp * RN + rid] = mold[r];
            Lp[sp * RN + rid] = lrow[r];
        }
    }
}

// Combine split partials -> AT bf16 [b][t][C]. One thread per (rid, 8-chan).
__global__ __launch_bounds__(256) void attn_combine(
        const bf16* __restrict__ Op, const float* __restrict__ Mp,
        const float* __restrict__ Lp, bf16* __restrict__ AT) {
    int i = blockIdx.x * 256 + threadIdx.x;       // < RN*12
    int rid = i / 12, j = i - rid * 12;
    float m[NSPLIT], l[NSPLIT], mx = -3.0e38f;
#pragma unroll
    for (int s = 0; s < NSPLIT; ++s) {
        m[s] = Mp[s * RN + rid];
        l[s] = Lp[s * RN + rid];
        mx = fmaxf(mx, m[s]);
    }
    float denom = 0.f;
    float o[8] = {};
#pragma unroll
    for (int s = 0; s < NSPLIT; ++s) {
        float sc = __expf(m[s] - mx);
        denom += sc * l[s];
        short8 v = *(const short8*)(Op + ((size_t)s * RN + rid) * 96 + j * 8);
        const bf16* vb = (const bf16*)&v;
#pragma unroll
        for (int e = 0; e < 8; ++e) o[e] += sc * __bfloat162float(vb[e]);
    }
    float inv = 1.f / denom;
    int t = rid & (Tn - 1), h = (rid >> 10) & (Hn - 1), b = rid >> 11;
    bf16 outv[8];
#pragma unroll
    for (int e = 0; e < 8; ++e) outv[e] = __float2bfloat16(o[e] * inv);
    *(uint4*)(AT + ((size_t)b * Tn + t) * Cn + h * DKn + j * 8) = *(uint4*)outv;
}

// ---------------------------------------------------------------------------
// Residual add + LayerNorm over channels. X <- LN(X+Y)*g+b (fp32) and
// XT <- bf16 transposed [b][t][C], optionally *mask.
__global__ __launch_bounds__(256) void ln_k(
        float* __restrict__ X, const float* __restrict__ Y,
        const float* __restrict__ G, const float* __restrict__ Bt,
        const float* __restrict__ mask, bf16* __restrict__ XT, int apply_mask) {
    __shared__ float tile[Cn][33];
    __shared__ float r1[8][32];
    __shared__ float r2[8][32];
    const int tid = threadIdx.x;
    const int lane = tid & 31, w = tid >> 5;
    const int b = blockIdx.x >> 5;
    const int t0 = (blockIdx.x & 31) * 32;
    const int t = t0 + lane;

    float s1 = 0.f, s2 = 0.f;
    for (int c = w; c < Cn; c += 8) {
        float v = X[((b * Cn + c) * Tn) + t] + Y[((b * Cn + c) * Tn) + t];
        tile[c][lane] = v;
        s1 += v;
        s2 += v * v;
    }
    r1[w][lane] = s1;
    r2[w][lane] = s2;
    __syncthreads();
    if (w == 0) {
        float a = 0.f, q = 0.f;
        for (int i = 0; i < 8; ++i) { a += r1[i][lane]; q += r2[i][lane]; }
        float m = a / Cn;
        float var = q / Cn - m * m;
        r1[0][lane] = m;
        r2[0][lane] = rsqrtf(var + 1e-5f);
    }
    __syncthreads();
    const float m = r1[0][lane], rs = r2[0][lane];
    for (int c = w; c < Cn; c += 8) {
        float y = (tile[c][lane] - m) * rs * G[c] + Bt[c];
        X[((b * Cn + c) * Tn) + t] = y;
        tile[c][lane] = y;
    }
    __syncthreads();
    for (int idx = tid; idx < 32 * Cn; idx += 256) {
        int tl = idx / Cn, c = idx % Cn;
        float v = tile[c][tl];
        if (apply_mask) v *= mask[b * Tn + t0 + tl];
        XT[((size_t)b * Tn + t0 + tl) * Cn + c] = __float2bfloat16(v);
    }
}

// FFN2-combine + residual + LN2: Y = (P0+P1+bias)*mask; Xn = LN(X+Y)*g+b.
// OUT==null: X <- Xn, XT <- bf16(Xn).  OUT!=null (last layer): OUT <- Xn*mask.
__global__ __launch_bounds__(256) void ln_ffn2(
        float* __restrict__ X, const float* __restrict__ P0,
        const float* __restrict__ P1, const float* __restrict__ bias,
        const float* __restrict__ G, const float* __restrict__ Bt,
        const float* __restrict__ mask, bf16* __restrict__ XT,
        float* __restrict__ OUT) {
    __shared__ float tile[Cn][33];
    __shared__ float r1[8][32];
    __shared__ float r2[8][32];
    const int tid = threadIdx.x;
    const int lane = tid & 31, w = tid >> 5;
    const int b = blockIdx.x >> 5;
    const int t0 = (blockIdx.x & 31) * 32;
    const int t = t0 + lane;
    const float mk = mask[b * Tn + t];

    float s1 = 0.f, s2 = 0.f;
    for (int c = w; c < Cn; c += 8) {
        size_t i = ((size_t)b * Cn + c) * Tn + t;
        float y = (P0[i] + P1[i] + bias[c]) * mk;
        float v = X[i] + y;
        tile[c][lane] = v;
        s1 += v;
        s2 += v * v;
    }
    r1[w][lane] = s1;
    r2[w][lane] = s2;
    __syncthreads();
    if (w == 0) {
        float a = 0.f, q = 0.f;
        for (int i = 0; i < 8; ++i) { a += r1[i][lane]; q += r2[i][lane]; }
        float m = a / Cn;
        float var = q / Cn - m * m;
        r1[0][lane] = m;
        r2[0][lane] = rsqrtf(var + 1e-5f);
    }
    __syncthreads();
    const float m = r1[0][lane], rs = r2[0][lane];
    if (OUT) {   // final layer: write output = LN(...)*mask directly, done
        for (int c = w; c < Cn; c += 8) {
            float y = (tile[c][lane] - m) * rs * G[c] + Bt[c];
            OUT[((b * Cn + c) * Tn) + t] = y * mk;
        }
        return;
    }
    for (int c = w; c < Cn; c += 8) {
        float y = (tile[c][lane] - m) * rs * G[c] + Bt[c];
        X[((b * Cn + c) * Tn) + t] = y;
        tile[c][lane] = y;
    }
    __syncthreads();
    for (int idx = tid; idx < 32 * Cn; idx += 256) {
        int tl = idx / Cn, c = idx % Cn;
        XT[((size_t)b * Tn + t0 + tl) * Cn + c] = __float2bfloat16(tile[c][tl]);
    }
}

// ---------------------------------------------------------------------------
extern "C" void kernel_launch(void* const* d_in, const int* in_sizes, int n_in,
                              void* d_out, int out_size, void* d_ws, size_t ws_size,
                              hipStream_t stream) {
    const float* x    = (const float*)d_in[0];
    const float* mask = (const float*)d_in[1];
    const float* Wq   = (const float*)d_in[2];
    const float* bq   = (const float*)d_in[3];
    const float* Wk   = (const float*)d_in[4];
    const float* bk   = (const float*)d_in[5];
    const float* Wv   = (const float*)d_in[6];
    const float* bv   = (const float*)d_in[7];
    const float* Wo   = (const float*)d_in[8];
    const float* bo   = (const float*)d_in[9];
    const float* erk  = (const float*)d_in[10];
    const float* erv  = (const float*)d_in[11];
    const float* ln1g = (const float*)d_in[12];
    const float* ln1b = (const float*)d_in[13];
    const float* w1   = (const float*)d_in[14];
    const float* b1   = (const float*)d_in[15];
    const float* w2   = (const float*)d_in[16];
    const float* b2   = (const float*)d_in[17];
    const float* ln2g = (const float*)d_in[18];
    const float* ln2b = (const float*)d_in[19];

    const size_t N = (size_t)Bn * Cn * Tn;         // 1,572,864
    const int WC = Ln * Cn * Cn;                   // 221,184
    const size_t WF = (size_t)Ln * 3 * FCn * Cn;   // 2,654,208
    const size_t WQKV = (size_t)Ln * 576 * Cn;     // 663,552
    const size_t NSCR = (size_t)Bn * Tn * FCn;     // 6,291,456 == NSPLIT*RN*96

    float* X    = (float*)d_ws;
    float* Yb   = X + N;                           // conv_o out / FFN2 partial 0
    float* bqkv = Yb + N;                          // L*576 floats
    float* Mp   = bqkv + Ln * 576;                 // NSPLIT*RN floats
    float* Lp   = Mp + (size_t)NSPLIT * RN;
    bf16* p16 = (bf16*)(Lp + (size_t)NSPLIT * RN);
    bf16* XT   = p16; p16 += N;
    bf16* QKT  = p16; p16 += (size_t)Bn * Tn * QKS;  // 2N bf16; dead after attn
    bf16* Vb   = p16; p16 += N;
    bf16* AT   = p16; p16 += N;
    bf16* SCR  = p16; p16 += NSCR;   // shared: attn O-partials <-> FFN hidden
    bf16* Wqkv = p16; p16 += WQKV;
    bf16* Wob  = p16; p16 += WC;
    bf16* W1t  = p16; p16 += WF;
    bf16* W2t  = p16; p16 += WF;
    bf16* ERKB = p16; p16 += Ln * 16 * 96;
    float* P1  = (float*)QKT;        // FFN2 partial 1 aliases dead QKT (N fp32)

    const float qscale = 0.10206207261596575f;  // 1/sqrt(96)

    // one-time transforms
    qkv_prep<<<(int)((WQKV + Ln * 576 + 255) / 256), 256, 0, stream>>>(
        Wq, Wk, Wv, bq, bk, bv, Wqkv, bqkv, qscale);
    cast_bf<<<(WC + 255) / 256, 256, 0, stream>>>(Wo, Wob, WC);
    reorder_w<<<(int)((WF + 255) / 256), 256, 0, stream>>>(w1, W1t, FCn, Cn);
    reorder_w<<<(int)((WF + 255) / 256), 256, 0, stream>>>(w2, W2t, Cn, FCn);
    erk_prep<<<(Ln * 16 * 96 + 255) / 256, 256, 0, stream>>>(erk, ERKB);
    cvt_in_k<<<Bn * 32, 256, 0, stream>>>(x, mask, X, XT);

    for (int l = 0; l < Ln; ++l) {
        conv_mfma<1, 64, 4, 1><<<dim3(Tn / 64, 9, Bn), 256, 0, stream>>>(
            XT, Wqkv + (size_t)l * 576 * Cn, bqkv + l * 576, nullptr, QKT, Vb, Cn, 576);
        attn_mfma<<<dim3(Tn / 64, Hn, Bn * NSPLIT), 256, 0, stream>>>(
            QKT, Vb, mask, ERKB, erv, SCR, Mp, Lp, l);
        attn_combine<<<RN * 12 / 256, 256, 0, stream>>>(SCR, Mp, Lp, AT);
        conv_mfma<1, 32, 0, 1><<<dim3(Tn / 32, 3, Bn), 256, 0, stream>>>(
            AT, Wob + (size_t)l * Cn * Cn, bo + l * Cn, nullptr, Yb, nullptr, Cn, Cn);
        ln_k<<<Bn * 32, 256, 0, stream>>>(X, Yb, ln1g + l * Cn, ln1b + l * Cn, mask, XT, 1);
        conv_mfma<3, 64, 2, 1><<<dim3(Tn / 64, FCn / 64, Bn), 256, 0, stream>>>(
            XT, W1t + (size_t)l * 3 * FCn * Cn, b1 + l * FCn, mask, SCR, nullptr, Cn, FCn);
        conv_mfma<3, 64, 5, 2><<<dim3(Tn / 64, 3, Bn * 2), 256, 0, stream>>>(
            SCR, W2t + (size_t)l * 3 * Cn * FCn, b2 + l * Cn, mask, Yb, P1, FCn, Cn);
        ln_ffn2<<<Bn * 32, 256, 0, stream>>>(X, Yb, P1, b2 + l * Cn,
                                             ln2g + l * Cn, ln2b + l * Cn, mask, XT,
                                             (l == Ln - 1) ? (float*)d_out : nullptr);
    }
}

// Round 15
// 1016.579 us; speedup vs baseline: 1.8153x; 1.0026x over previous
//
#include <hip/hip_runtime.h>
#include <hip/hip_bf16.h>

// Problem constants
constexpr int Bn  = 8;
constexpr int Cn  = 192;   // hidden channels
constexpr int Tn  = 1024;  // sequence length
constexpr int Hn  = 2;     // heads
constexpr int DKn = 96;    // head dim
constexpr int FCn = 768;   // filter channels
constexpr int Ln  = 6;     // layers
constexpr int WINn = 4;    // rel-attn window
constexpr int QKS = 384;   // QK transposed row stride (Q|K concat)
constexpr int NSPLIT = 4;  // attention s-split (flash-decoding)
constexpr int RN  = Bn * Hn * Tn;  // 16384 attention rows

typedef __hip_bfloat16 bf16;
typedef __attribute__((ext_vector_type(8))) short short8;
typedef __attribute__((ext_vector_type(4))) float f32x4;

// ---------------------------------------------------------------------------
// One-time transforms
__global__ void cast_bf(const float* __restrict__ src, bf16* __restrict__ dst, int n) {
    int i = blockIdx.x * 256 + threadIdx.x;
    if (i < n) dst[i] = __float2bfloat16(src[i]);
}

// w [L][CO][CIN][3] -> [L][3][CO][CIN] bf16
__global__ void reorder_w(const float* __restrict__ src, bf16* __restrict__ dst,
                          int CO, int CIN) {
    int i = blockIdx.x * 256 + threadIdx.x;
    int n = Ln * 3 * CO * CIN;
    if (i >= n) return;
    int c = i % CIN;
    int f = (i / CIN) % CO;
    int ko = (i / (CIN * CO)) % 3;
    int l = i / (3 * CIN * CO);
    dst[i] = __float2bfloat16(src[(((size_t)(l * CO + f)) * CIN + c) * 3 + ko]);
}

// erk fp32 [L][9][96] -> bf16 [L][16][96], rows 9..15 zero (MFMA B-frag ready)
__global__ void erk_prep(const float* __restrict__ src, bf16* __restrict__ dst) {
    int i = blockIdx.x * 256 + threadIdx.x;       // < Ln*16*96
    if (i >= Ln * 16 * 96) return;
    int d = i % 96, row = (i / 96) % 16, l = i / (96 * 16);
    float v = (row < 9) ? src[((size_t)l * 9 + row) * 96 + d] : 0.f;
    dst[i] = __float2bfloat16(v);
}

// Build fused QKV weight [L][576][C] bf16 (qscale folded into Q) + bias fp32
__global__ void qkv_prep(const float* __restrict__ Wq, const float* __restrict__ Wk,
                         const float* __restrict__ Wv, const float* __restrict__ bq,
                         const float* __restrict__ bk, const float* __restrict__ bv,
                         bf16* __restrict__ Wout, float* __restrict__ bout, float qscale) {
    int i = blockIdx.x * 256 + threadIdx.x;
    const int nW = Ln * 576 * Cn;
    if (i < nW) {
        int c = i % Cn, f = (i / Cn) % 576, l = i / (Cn * 576);
        float v;
        if (f < 192)      v = Wq[((size_t)l * Cn + f) * Cn + c] * qscale;
        else if (f < 384) v = Wk[((size_t)l * Cn + f - 192) * Cn + c];
        else              v = Wv[((size_t)l * Cn + f - 384) * Cn + c];
        Wout[i] = __float2bfloat16(v);
    } else if (i < nW + Ln * 576) {
        int j = i - nW, f = j % 576, l = j / 576;
        float v;
        if (f < 192)      v = bq[l * Cn + f] * qscale;
        else if (f < 384) v = bk[l * Cn + f - 192];
        else              v = bv[l * Cn + f - 384];
        bout[j] = v;
    }
}

// ---------------------------------------------------------------------------
// Input: X = x*mask (fp32, NCT) + XT = bf16 transposed [b][t][c]
__global__ __launch_bounds__(256) void cvt_in_k(
        const float* __restrict__ x, const float* __restrict__ mask,
        float* __restrict__ X, bf16* __restrict__ XT) {
    __shared__ float tile[Cn][33];
    const int tid = threadIdx.x, lane = tid & 31, w = tid >> 5;
    const int b = blockIdx.x >> 5;
    const int t0 = (blockIdx.x & 31) * 32;
    const float mk = mask[b * Tn + t0 + lane];
    for (int c = w; c < Cn; c += 8) {
        float v = x[((b * Cn + c) * Tn) + t0 + lane] * mk;
        X[((b * Cn + c) * Tn) + t0 + lane] = v;
        tile[c][lane] = v;
    }
    __syncthreads();
    for (int idx = tid; idx < 32 * Cn; idx += 256) {
        int tl = idx / Cn, c = idx % Cn;
        XT[((size_t)b * Tn + t0 + tl) * Cn + c] = __float2bfloat16(tile[c][tl]);
    }
}

// ---------------------------------------------------------------------------
// MFMA conv1d, LDS-staged (m97 structure) — R12 winner, unchanged.
// MODE 0: fp32 NCT out (+bias, *mask if mask!=null)
// MODE 2: bf16 transposed [b][t][CO] out relu(+bias)*mask   [FFN1]
// MODE 4: QKV split: f<384 -> bf16 T (stride QKS) into Y0; else bf16 NCT Y1
// MODE 5: fp32 NCT K-split partial, NO bias: ks==0 -> Y0, ks==1 -> Y1 [FFN2]
template <int KS, int TT, int MODE, int NSP>
__global__ __launch_bounds__(256) void conv_mfma(
        const bf16* __restrict__ Xt, const bf16* __restrict__ W,
        const float* __restrict__ bias, const float* __restrict__ mask,
        void* __restrict__ Y0, void* __restrict__ Y1, int CIN, int CO) {
    constexpr int PAD = KS / 2;
    constexpr int NMB = TT / 16;
    constexpr int AR  = TT + KS - 1;   // A rows staged
    constexpr int RS  = 72;            // padded row stride (bf16 cols)
    __shared__ bf16 As[AR][RS];
    __shared__ bf16 Bs[KS][64][RS];

    const int tid = threadIdx.x;
    const int wv = tid >> 6, lane = tid & 63;
    const int m = lane & 15, kq = lane >> 4;
    const int b = blockIdx.z / NSP, ks = blockIdx.z % NSP;
    const int t0 = blockIdx.x * TT;
    const int f0 = blockIdx.y * 64;
    const int f = f0 + wv * 16 + m;

    const bf16* xb = Xt + (size_t)b * Tn * CIN;
    const size_t wko = (size_t)CO * CIN;

    f32x4 acc[NMB] = {};

    const int cbeg = ks * (CIN / NSP);
    const int cend = cbeg + CIN / NSP;
    for (int c0 = cbeg; c0 < cend; c0 += 64) {
        __syncthreads();   // previous chunk's fragment reads complete
        for (int s = tid; s < AR * 8; s += 256) {
            int r = s >> 3, cs = (s & 7) * 8;
            int gt = t0 + r - PAD;
            short8 v = {0, 0, 0, 0, 0, 0, 0, 0};
            if (PAD == 0 || (unsigned)gt < (unsigned)Tn)
                v = *(const short8*)(xb + (size_t)gt * CIN + c0 + cs);
            *(short8*)&As[r][cs] = v;
        }
        for (int s = tid; s < KS * 512; s += 256) {
            int ko = s >> 9, r = (s >> 3) & 63, cs = (s & 7) * 8;
            short8 v = *(const short8*)(W + (size_t)ko * wko + (size_t)(f0 + r) * CIN + c0 + cs);
            *(short8*)&Bs[ko][r][cs] = v;
        }
        __syncthreads();   // staged data visible
#pragma unroll
        for (int kk = 0; kk < 2; ++kk)
#pragma unroll
            for (int ko = 0; ko < KS; ++ko) {
                short8 bfr = *(const short8*)&Bs[ko][wv * 16 + m][kk * 32 + kq * 8];
#pragma unroll
                for (int mb = 0; mb < NMB; ++mb) {
                    short8 afr = *(const short8*)&As[mb * 16 + m + ko][kk * 32 + kq * 8];
                    acc[mb] = __builtin_amdgcn_mfma_f32_16x16x32_bf16(afr, bfr, acc[mb], 0, 0, 0);
                }
            }
    }

    if (MODE == 5) {
        float* Y = (float*)(ks ? Y1 : Y0) + ((size_t)b * CO + f) * Tn;
#pragma unroll
        for (int mb = 0; mb < NMB; ++mb) {
            int t = t0 + mb * 16 + kq * 4;
            float4 o;
            o.x = acc[mb][0]; o.y = acc[mb][1]; o.z = acc[mb][2]; o.w = acc[mb][3];
            *(float4*)(Y + t) = o;
        }
        return;
    }
    const float bs = bias[f];
    if (MODE == 0) {
        float* Y = (float*)Y0 + ((size_t)b * CO + f) * Tn;
#pragma unroll
        for (int mb = 0; mb < NMB; ++mb) {
            int t = t0 + mb * 16 + kq * 4;
            float4 o;
            o.x = acc[mb][0] + bs; o.y = acc[mb][1] + bs;
            o.z = acc[mb][2] + bs; o.w = acc[mb][3] + bs;
            if (mask) {
                o.x *= mask[b * Tn + t];     o.y *= mask[b * Tn + t + 1];
                o.z *= mask[b * Tn + t + 2]; o.w *= mask[b * Tn + t + 3];
            }
            *(float4*)(Y + t) = o;
        }
    } else if (MODE == 2) {
        bf16* Y = (bf16*)Y0;
#pragma unroll
        for (int mb = 0; mb < NMB; ++mb)
#pragma unroll
            for (int r = 0; r < 4; ++r) {
                int t = t0 + mb * 16 + kq * 4 + r;
                float v = fmaxf(acc[mb][r] + bs, 0.f) * mask[b * Tn + t];
                Y[((size_t)b * Tn + t) * CO + f] = __float2bfloat16(v);
            }
    } else {  // MODE 4
        if (blockIdx.y < 6) {          // Q|K -> transposed, stride QKS
            bf16* Y = (bf16*)Y0;
#pragma unroll
            for (int mb = 0; mb < NMB; ++mb)
#pragma unroll
                for (int r = 0; r < 4; ++r) {
                    int t = t0 + mb * 16 + kq * 4 + r;
                    Y[((size_t)b * Tn + t) * QKS + f] = __float2bfloat16(acc[mb][r] + bs);
                }
        } else {                        // V -> bf16 NCT
            bf16* Y = (bf16*)Y1 + ((size_t)b * Cn + f - 384) * Tn;
#pragma unroll
            for (int mb = 0; mb < NMB; ++mb) {
                int t = t0 + mb * 16 + kq * 4;
                bf16 tmp[4];
#pragma unroll
                for (int r = 0; r < 4; ++r) tmp[r] = __float2bfloat16(acc[mb][r] + bs);
                *(uint2*)(Y + t) = *(uint2*)tmp;
            }
        }
    }
}

// ---------------------------------------------------------------------------
// MFMA flash attention, split-K over s, LDS-staged K/V, FIXED-MAX softmax.
// Scores are O(5) (layernormed inputs, 1/sqrt(dk) folded into Q), so
// exp(s) is safely in fp32 range: drop online-max tracking entirely
// (mathematically exact — exp(s)/sum exp(s)). No Mp.
// Padding: Ks 100 (stride 50 banks), Vs/pT 68 (stride 34 ≡ 2 mod 32) —
// ≤2-way aliasing (free per m136).
// Writes UNNORMALIZED partials: Op bf16 [sp][rid][96], Lp fp32 [sp][rid].
__global__ __launch_bounds__(256) void attn_mfma(
        const bf16* __restrict__ QK, const bf16* __restrict__ V,
        const float* __restrict__ mask, const bf16* __restrict__ erkb,
        const float* __restrict__ erv, bf16* __restrict__ Op,
        float* __restrict__ Lp, int layer) {
    __shared__ bf16 Ks[64][100];      // K chunk [s][d]
    __shared__ bf16 Vs[96][68];       // V chunk [d][s]
    __shared__ float rq[4][16][17];   // per-wave rel-K band: [m][dd]
    __shared__ bf16 pT[4][16][68];    // per-wave P: [m][s]

    const int tid = threadIdx.x, wv = tid >> 6, lane = tid & 63;
    const int col = lane & 15, quad = lane >> 4;
    const int t0 = blockIdx.x * 64, h = blockIdx.y;
    const int b = blockIdx.z / NSPLIT, sp = blockIdx.z % NSPLIT;
    const int hd = h * DKn;
    const int t0w = t0 + wv * 16;

    // Q A-frags (persist): A[m=col][k=quad*8+j+32*kd]
    short8 aq[3];
    {
        const bf16* qrow = QK + ((size_t)b * Tn + t0w + col) * QKS + hd + quad * 8;
#pragma unroll
        for (int kd = 0; kd < 3; ++kd) aq[kd] = *(const short8*)(qrow + kd * 32);
    }
    // rel-K band via MFMA: R = Q . erk^T  (B rows 9..15 are zero)
    {
        const bf16* erow = erkb + ((size_t)layer * 16 + col) * 96 + quad * 8;
        f32x4 R = {};
#pragma unroll
        for (int kd = 0; kd < 3; ++kd) {
            short8 be = *(const short8*)(erow + kd * 32);
            R = __builtin_amdgcn_mfma_f32_16x16x32_bf16(aq[kd], be, R, 0, 0, 0);
        }
#pragma unroll
        for (int r = 0; r < 4; ++r) rq[wv][quad * 4 + r][col] = R[r];
    }
    float mtv[4];
#pragma unroll
    for (int r = 0; r < 4; ++r) mtv[r] = mask[b * Tn + t0w + quad * 4 + r];

    float lrow[4] = {};
    f32x4 O[6] = {};
    const float* ervl = erv + (size_t)layer * 9 * DKn;

    const int sbeg = sp * (Tn / NSPLIT);
    const int send = sbeg + Tn / NSPLIT;
    for (int s0 = sbeg; s0 < send; s0 += 64) {
        __syncthreads();   // previous chunk's Ks/Vs reads complete
        // stage K: 64 rows (s) x 96 cols (d), 12 short8/row, coalesced
        for (int s = tid; s < 768; s += 256) {
            int r = s / 12, cs = (s % 12) * 8;
            *(short8*)&Ks[r][cs] =
                *(const short8*)(QK + ((size_t)b * Tn + s0 + r) * QKS + 192 + hd + cs);
        }
        // stage V: 96 rows (d) x 64 cols (s), 8 short8/row, coalesced
        for (int s = tid; s < 768; s += 256) {
            int r = s >> 3, cs = (s & 7) * 8;
            *(short8*)&Vs[r][cs] =
                *(const short8*)(V + ((size_t)(b * Cn + hd + r)) * Tn + s0 + cs);
        }
        __syncthreads();   // staged data visible

        // S = Q K^T (B-frags from LDS)
        f32x4 S[4] = {};
#pragma unroll
        for (int nb = 0; nb < 4; ++nb)
#pragma unroll
            for (int kd = 0; kd < 3; ++kd) {
                short8 bkf = *(const short8*)&Ks[16 * nb + col][kd * 32 + quad * 8];
                S[nb] = __builtin_amdgcn_mfma_f32_16x16x32_bf16(aq[kd], bkf, S[nb], 0, 0, 0);
            }

#pragma unroll
        for (int nb = 0; nb < 4; ++nb) {
            const int sg = s0 + 16 * nb + col;
            const float msv = mask[b * Tn + sg];
#pragma unroll
            for (int r = 0; r < 4; ++r) {
                const int tq = t0w + quad * 4 + r;
                float v = S[nb][r];
                int dd = sg - tq + WINn;
                if (dd >= 0 && dd <= 2 * WINn) v += rq[wv][quad * 4 + r][dd];
                if (msv * mtv[r] == 0.f) v = -1e4f;
                S[nb][r] = v;
            }
        }

        // fixed-max softmax: P = exp(S); row-sum via 16-lane shuffle reduce
        float psum[4] = {};
#pragma unroll
        for (int nb = 0; nb < 4; ++nb)
#pragma unroll
            for (int r = 0; r < 4; ++r) {
                bf16 pb = __float2bfloat16(__expf(S[nb][r]));
                pT[wv][quad * 4 + r][16 * nb + col] = pb;
                psum[r] += __bfloat162float(pb);
            }
#pragma unroll
        for (int r = 0; r < 4; ++r) {
#pragma unroll
            for (int mk2 = 1; mk2 < 16; mk2 <<= 1) psum[r] += __shfl_xor(psum[r], mk2);
            lrow[r] += psum[r];
        }

        // P A-frags from per-wave LDS; PV (V B-frags from shared LDS)
        short8 aP[2];
#pragma unroll
        for (int kk = 0; kk < 2; ++kk)
            aP[kk] = *(const short8*)&pT[wv][col][kk * 32 + quad * 8];
#pragma unroll
        for (int nd = 0; nd < 6; ++nd)
#pragma unroll
            for (int kk = 0; kk < 2; ++kk) {
                short8 bvf = *(const short8*)&Vs[16 * nd + col][kk * 32 + quad * 8];
                O[nd] = __builtin_amdgcn_mfma_f32_16x16x32_bf16(aP[kk], bvf, O[nd], 0, 0, 0);
            }

        // rel-V on diagonal chunks
        if (s0 <= t0w + 15 + WINn && s0 + 63 >= t0w - WINn) {
#pragma unroll
            for (int r = 0; r < 4; ++r) {
                const int tq = t0w + quad * 4 + r;
                for (int dd = 0; dd <= 2 * WINn; ++dd) {
                    int sg = tq + dd - WINn;
                    if (sg >= s0 && sg < s0 + 64) {
                        float p = __bfloat162float(pT[wv][quad * 4 + r][sg - s0]);
#pragma unroll
                        for (int nd = 0; nd < 6; ++nd)
                            O[nd][r] += p * ervl[dd * DKn + 16 * nd + col];
                    }
                }
            }
        }
    }

    // epilogue: write unnormalized partials
    const int rbase = (b * Hn + h) * Tn + t0w;
#pragma unroll
    for (int r = 0; r < 4; ++r) {
        const int rid = rbase + quad * 4 + r;
        bf16* dst = Op + ((size_t)sp * RN + rid) * 96 + col;
#pragma unroll
        for (int nd = 0; nd < 6; ++nd)
            dst[16 * nd] = __float2bfloat16(O[nd][r]);
        if (col == 0) Lp[sp * RN + rid] = lrow[r];
    }
}

// Combine split partials -> AT bf16 [b][t][C]. One thread per (rid, 8-chan).
__global__ __launch_bounds__(256) void attn_combine(
        const bf16* __restrict__ Op, const float* __restrict__ Lp,
        bf16* __restrict__ AT) {
    int i = blockIdx.x * 256 + threadIdx.x;       // < RN*12
    int rid = i / 12, j = i - rid * 12;
    float denom = 0.f;
    float o[8] = {};
#pragma unroll
    for (int s = 0; s < NSPLIT; ++s) {
        denom += Lp[s * RN + rid];
        short8 v = *(const short8*)(Op + ((size_t)s * RN + rid) * 96 + j * 8);
        const bf16* vb = (const bf16*)&v;
#pragma unroll
        for (int e = 0; e < 8; ++e) o[e] += __bfloat162float(vb[e]);
    }
    float inv = 1.f / fmaxf(denom, 1e-30f);
    int t = rid & (Tn - 1), h = (rid >> 10) & (Hn - 1), b = rid >> 11;
    bf16 outv[8];
#pragma unroll
    for (int e = 0; e < 8; ++e) outv[e] = __float2bfloat16(o[e] * inv);
    *(uint4*)(AT + ((size_t)b * Tn + t) * Cn + h * DKn + j * 8) = *(uint4*)outv;
}

// ---------------------------------------------------------------------------
// Residual add + LayerNorm over channels. X <- LN(X+Y)*g+b (fp32) and
// XT <- bf16 transposed [b][t][C], optionally *mask.
__global__ __launch_bounds__(256) void ln_k(
        float* __restrict__ X, const float* __restrict__ Y,
        const float* __restrict__ G, const float* __restrict__ Bt,
        const float* __restrict__ mask, bf16* __restrict__ XT, int apply_mask) {
    __shared__ float tile[Cn][33];
    __shared__ float r1[8][32];
    __shared__ float r2[8][32];
    const int tid = threadIdx.x;
    const int lane = tid & 31, w = tid >> 5;
    const int b = blockIdx.x >> 5;
    const int t0 = (blockIdx.x & 31) * 32;
    const int t = t0 + lane;

    float s1 = 0.f, s2 = 0.f;
    for (int c = w; c < Cn; c += 8) {
        float v = X[((b * Cn + c) * Tn) + t] + Y[((b * Cn + c) * Tn) + t];
        tile[c][lane] = v;
        s1 += v;
        s2 += v * v;
    }
    r1[w][lane] = s1;
    r2[w][lane] = s2;
    __syncthreads();
    if (w == 0) {
        float a = 0.f, q = 0.f;
        for (int i = 0; i < 8; ++i) { a += r1[i][lane]; q += r2[i][lane]; }
        float m = a / Cn;
        float var = q / Cn - m * m;
        r1[0][lane] = m;
        r2[0][lane] = rsqrtf(var + 1e-5f);
    }
    __syncthreads();
    const float m = r1[0][lane], rs = r2[0][lane];
    for (int c = w; c < Cn; c += 8) {
        float y = (tile[c][lane] - m) * rs * G[c] + Bt[c];
        X[((b * Cn + c) * Tn) + t] = y;
        tile[c][lane] = y;
    }
    __syncthreads();
    for (int idx = tid; idx < 32 * Cn; idx += 256) {
        int tl = idx / Cn, c = idx % Cn;
        float v = tile[c][tl];
        if (apply_mask) v *= mask[b * Tn + t0 + tl];
        XT[((size_t)b * Tn + t0 + tl) * Cn + c] = __float2bfloat16(v);
    }
}

// FFN2-combine + residual + LN2: Y = (P0+P1+bias)*mask; Xn = LN(X+Y)*g+b.
// OUT==null: X <- Xn, XT <- bf16(Xn).  OUT!=null (last layer): OUT <- Xn*mask.
__global__ __launch_bounds__(256) void ln_ffn2(
        float* __restrict__ X, const float* __restrict__ P0,
        const float* __restrict__ P1, const float* __restrict__ bias,
        const float* __restrict__ G, const float* __restrict__ Bt,
        const float* __restrict__ mask, bf16* __restrict__ XT,
        float* __restrict__ OUT) {
    __shared__ float tile[Cn][33];
    __shared__ float r1[8][32];
    __shared__ float r2[8][32];
    const int tid = threadIdx.x;
    const int lane = tid & 31, w = tid >> 5;
    const int b = blockIdx.x >> 5;
    const int t0 = (blockIdx.x & 31) * 32;
    const int t = t0 + lane;
    const float mk = mask[b * Tn + t];

    float s1 = 0.f, s2 = 0.f;
    for (int c = w; c < Cn; c += 8) {
        size_t i = ((size_t)b * Cn + c) * Tn + t;
        float y = (P0[i] + P1[i] + bias[c]) * mk;
        float v = X[i] + y;
        tile[c][lane] = v;
        s1 += v;
        s2 += v * v;
    }
    r1[w][lane] = s1;
    r2[w][lane] = s2;
    __syncthreads();
    if (w == 0) {
        float a = 0.f, q = 0.f;
        for (int i = 0; i < 8; ++i) { a += r1[i][lane]; q += r2[i][lane]; }
        float m = a / Cn;
        float var = q / Cn - m * m;
        r1[0][lane] = m;
        r2[0][lane] = rsqrtf(var + 1e-5f);
    }
    __syncthreads();
    const float m = r1[0][lane], rs = r2[0][lane];
    if (OUT) {   // final layer: write output = LN(...)*mask directly, done
        for (int c = w; c < Cn; c += 8) {
            float y = (tile[c][lane] - m) * rs * G[c] + Bt[c];
            OUT[((b * Cn + c) * Tn) + t] = y * mk;
        }
        return;
    }
    for (int c = w; c < Cn; c += 8) {
        float y = (tile[c][lane] - m) * rs * G[c] + Bt[c];
        X[((b * Cn + c) * Tn) + t] = y;
        tile[c][lane] = y;
    }
    __syncthreads();
    for (int idx = tid; idx < 32 * Cn; idx += 256) {
        int tl = idx / Cn, c = idx % Cn;
        XT[((size_t)b * Tn + t0 + tl) * Cn + c] = __float2bfloat16(tile[c][tl]);
    }
}

// ---------------------------------------------------------------------------
extern "C" void kernel_launch(void* const* d_in, const int* in_sizes, int n_in,
                              void* d_out, int out_size, void* d_ws, size_t ws_size,
                              hipStream_t stream) {
    const float* x    = (const float*)d_in[0];
    const float* mask = (const float*)d_in[1];
    const float* Wq   = (const float*)d_in[2];
    const float* bq   = (const float*)d_in[3];
    const float* Wk   = (const float*)d_in[4];
    const float* bk   = (const float*)d_in[5];
    const float* Wv   = (const float*)d_in[6];
    const float* bv   = (const float*)d_in[7];
    const float* Wo   = (const float*)d_in[8];
    const float* bo   = (const float*)d_in[9];
    const float* erk  = (const float*)d_in[10];
    const float* erv  = (const float*)d_in[11];
    const float* ln1g = (const float*)d_in[12];
    const float* ln1b = (const float*)d_in[13];
    const float* w1   = (const float*)d_in[14];
    const float* b1   = (const float*)d_in[15];
    const float* w2   = (const float*)d_in[16];
    const float* b2   = (const float*)d_in[17];
    const float* ln2g = (const float*)d_in[18];
    const float* ln2b = (const float*)d_in[19];

    const size_t N = (size_t)Bn * Cn * Tn;         // 1,572,864
    const int WC = Ln * Cn * Cn;                   // 221,184
    const size_t WF = (size_t)Ln * 3 * FCn * Cn;   // 2,654,208
    const size_t WQKV = (size_t)Ln * 576 * Cn;     // 663,552
    const size_t NSCR = (size_t)Bn * Tn * FCn;     // 6,291,456 == NSPLIT*RN*96

    float* X    = (float*)d_ws;
    float* Yb   = X + N;                           // conv_o out / FFN2 partial 0
    float* bqkv = Yb + N;                          // L*576 floats
    float* Lp   = bqkv + Ln * 576;                 // NSPLIT*RN floats
    bf16* p16 = (bf16*)(Lp + (size_t)NSPLIT * RN);
    bf16* XT   = p16; p16 += N;
    bf16* QKT  = p16; p16 += (size_t)Bn * Tn * QKS;  // 2N bf16; dead after attn
    bf16* Vb   = p16; p16 += N;
    bf16* AT   = p16; p16 += N;
    bf16* SCR  = p16; p16 += NSCR;   // shared: attn O-partials <-> FFN hidden
    bf16* Wqkv = p16; p16 += WQKV;
    bf16* Wob  = p16; p16 += WC;
    bf16* W1t  = p16; p16 += WF;
    bf16* W2t  = p16; p16 += WF;
    bf16* ERKB = p16; p16 += Ln * 16 * 96;
    float* P1  = (float*)QKT;        // FFN2 partial 1 aliases dead QKT (N fp32)

    const float qscale = 0.10206207261596575f;  // 1/sqrt(96)

    // one-time transforms
    qkv_prep<<<(int)((WQKV + Ln * 576 + 255) / 256), 256, 0, stream>>>(
        Wq, Wk, Wv, bq, bk, bv, Wqkv, bqkv, qscale);
    cast_bf<<<(WC + 255) / 256, 256, 0, stream>>>(Wo, Wob, WC);
    reorder_w<<<(int)((WF + 255) / 256), 256, 0, stream>>>(w1, W1t, FCn, Cn);
    reorder_w<<<(int)((WF + 255) / 256), 256, 0, stream>>>(w2, W2t, Cn, FCn);
    erk_prep<<<(Ln * 16 * 96 + 255) / 256, 256, 0, stream>>>(erk, ERKB);
    cvt_in_k<<<Bn * 32, 256, 0, stream>>>(x, mask, X, XT);

    for (int l = 0; l < Ln; ++l) {
        conv_mfma<1, 64, 4, 1><<<dim3(Tn / 64, 9, Bn), 256, 0, stream>>>(
            XT, Wqkv + (size_t)l * 576 * Cn, bqkv + l * 576, nullptr, QKT, Vb, Cn, 576);
        attn_mfma<<<dim3(Tn / 64, Hn, Bn * NSPLIT), 256, 0, stream>>>(
            QKT, Vb, mask, ERKB, erv, SCR, Lp, l);
        attn_combine<<<RN * 12 / 256, 256, 0, stream>>>(SCR, Lp, AT);
        conv_mfma<1, 32, 0, 1><<<dim3(Tn / 32, 3, Bn), 256, 0, stream>>>(
            AT, Wob + (size_t)l * Cn * Cn, bo + l * Cn, nullptr, Yb, nullptr, Cn, Cn);
        ln_k<<<Bn * 32, 256, 0, stream>>>(X, Yb, ln1g + l * Cn, ln1b + l * Cn, mask, XT, 1);
        conv_mfma<3, 64, 2, 1><<<dim3(Tn / 64, FCn / 64, Bn), 256, 0, stream>>>(
            XT, W1t + (size_t)l * 3 * FCn * Cn, b1 + l * FCn, mask, SCR, nullptr, Cn, FCn);
        conv_mfma<3, 64, 5, 2><<<dim3(Tn / 64, 3, Bn * 2), 256, 0, stream>>>(
            SCR, W2t + (size_t)l * 3 * Cn * FCn, b2 + l * Cn, mask, Yb, P1, FCn, Cn);
        ln_ffn2<<<Bn * 32, 256, 0, stream>>>(X, Yb, P1, b2 + l * Cn,
                                             ln2g + l * Cn, ln2b + l * Cn, mask, XT,
                                             (l == Ln - 1) ? (float*)d_out : nullptr);
    }
}